// Round 12
// baseline (786.690 us; speedup 1.0000x reference)
//
#include <hip/hip_runtime.h>
#include <math.h>

#define DD 256
#define NH 8
#define HDIM 32
#define NLAY 6
#define NQRY 100
#define TT 101
#define BB 8
#define NN 4096
#define NTXT 32
#define FFD 2048
#define MM (BB*TT)      // 808
#define MMP 896
#define BNN (BB*NN)     // 32768
#define KC 8
#define KPC (NN/KC)     // 512
#define D2 (DD*DD)
#define C1S 0.25506807170842403f   // (1/sqrt(32)) * log2(e)

typedef __bf16 bf16x8 __attribute__((ext_vector_type(8)));
typedef float f32x4v __attribute__((ext_vector_type(4)));
typedef unsigned int u32x4 __attribute__((ext_vector_type(4)));
typedef unsigned int u32x2 __attribute__((ext_vector_type(2)));

__device__ __forceinline__ ushort f2b(float f) {
  unsigned u = __builtin_bit_cast(unsigned, f);
  u += 0x7FFF + ((u >> 16) & 1);
  return (ushort)(u >> 16);
}
__device__ __forceinline__ unsigned pk2(float lo, float hi) {
  return (unsigned)f2b(lo) | ((unsigned)f2b(hi) << 16);
}
__device__ __forceinline__ f32x4v mfma16(bf16x8 a, bf16x8 b, f32x4v c) {
  return __builtin_amdgcn_mfma_f32_16x16x32_bf16(a, b, c, 0, 0, 0);
}

// ---- async global->LDS 16B, wave-uniform LDS base + lane*16 ----
__device__ __forceinline__ void gload16(const void* g, void* l) {
  __builtin_amdgcn_global_load_lds(
      (const __attribute__((address_space(1))) void*)g,
      (__attribute__((address_space(3))) void*)l, 16, 0, 0);
}

// ---- BK=64 stage: NROWS x 128B rows, XOR-16B swizzle via pre-swizzled source
template <int NROWS>
__device__ __forceinline__ void stage_sw(const ushort* __restrict__ G, size_t ldg,
                                         int row0, int k0, char* lds, int w, int l) {
  constexpr int RPW = NROWS / 4;
  constexpr int ISSUES = RPW / 8;
#pragma unroll
  for (int p = 0; p < ISSUES; ++p) {
    int slot = p * 64 + l;
    int row = w * RPW + (slot >> 3);
    int blk = slot & 7;
    int cb = blk ^ (row & 7);
    const ushort* src = G + (size_t)(row0 + row) * ldg + (size_t)k0 + cb * 8;
    char* db = lds + (w * RPW + p * 8) * 128;
    gload16(src, db);
  }
}

// ---- BK=128 stage: NROWS x 256B rows; swizzle within each 128B half
template <int NROWS>
__device__ __forceinline__ void stage2(const ushort* __restrict__ G, size_t ldg,
                                       int row0, int k0, char* lds, int w, int l) {
  constexpr int RPW = NROWS / 4;
  constexpr int ISSUES = RPW / 4;
#pragma unroll
  for (int p = 0; p < ISSUES; ++p) {
    int row = w * RPW + p * 4 + (l >> 4);
    int blk = l & 15;
    int cb = (blk & 8) | ((blk & 7) ^ (row & 7));
    const ushort* src = G + (size_t)(row0 + row) * ldg + (size_t)k0 + cb * 8;
    char* db = lds + (w * RPW + p * 4) * 256;
    gload16(src, db);
  }
}

// ---------------- BK=64 MFMA core (k_gemm_mem, K=64) ----------------
__device__ __forceinline__ void gemm_core(const ushort* __restrict__ A, size_t lda,
                                          const ushort* __restrict__ Bt, size_t ldb,
                                          int m0, int n0, int kBeg, int kEnd,
                                          char* AsB, char* BsB, int t,
                                          f32x4v acc[2][4]) {
  int w = t >> 6, l = t & 63, lq = l & 15, lg = l >> 4;
  for (int k0 = kBeg; k0 < kEnd; k0 += 64) {
    __syncthreads();
    stage_sw<128>(A, lda, m0, k0, AsB, w, l);
    stage_sw<64>(Bt, ldb, n0, k0, BsB, w, l);
    __syncthreads();
#pragma unroll
    for (int ks = 0; ks < 2; ++ks) {
      bf16x8 af[2], bfr[4];
#pragma unroll
      for (int mt = 0; mt < 2; ++mt) {
        int row = w * 32 + mt * 16 + lq;
        int kb = ks * 64 + lg * 16;
        af[mt] = __builtin_bit_cast(
            bf16x8, *(const u32x4*)(AsB + row * 128 + (kb ^ ((row & 7) << 4))));
      }
#pragma unroll
      for (int nt = 0; nt < 4; ++nt) {
        int row = nt * 16 + lq;
        int kb = ks * 64 + lg * 16;
        bfr[nt] = __builtin_bit_cast(
            bf16x8, *(const u32x4*)(BsB + row * 128 + (kb ^ ((row & 7) << 4))));
      }
#pragma unroll
      for (int mt = 0; mt < 2; ++mt)
#pragma unroll
        for (int nt = 0; nt < 4; ++nt) acc[mt][nt] = mfma16(af[mt], bfr[nt], acc[mt][nt]);
    }
  }
}

// ---------------- BK=128 MFMA core: 128x64 tile, 256B LDS rows ----------------
__device__ __forceinline__ void gemm_core128(const ushort* __restrict__ A, size_t lda,
                                             const ushort* __restrict__ Bt, size_t ldb,
                                             int m0, int n0, int kBeg, int kEnd,
                                             char* AsB, char* BsB, int t,
                                             f32x4v acc[2][4]) {
  int w = t >> 6, l = t & 63, lq = l & 15, lg = l >> 4;
  for (int k0 = kBeg; k0 < kEnd; k0 += 128) {
    __syncthreads();
    stage2<128>(A, lda, m0, k0, AsB, w, l);
    stage2<64>(Bt, ldb, n0, k0, BsB, w, l);
    __syncthreads();
#pragma unroll
    for (int ks = 0; ks < 4; ++ks) {
      int kb = ks * 64 + lg * 16;
      bf16x8 af[2], bfr[4];
#pragma unroll
      for (int mt = 0; mt < 2; ++mt) {
        int row = w * 32 + mt * 16 + lq;
        af[mt] = __builtin_bit_cast(
            bf16x8, *(const u32x4*)(AsB + row * 256 + (kb ^ ((row & 7) << 4))));
      }
#pragma unroll
      for (int nt = 0; nt < 4; ++nt) {
        int row = nt * 16 + lq;
        bfr[nt] = __builtin_bit_cast(
            bf16x8, *(const u32x4*)(BsB + row * 256 + (kb ^ ((row & 7) << 4))));
      }
#pragma unroll
      for (int mt = 0; mt < 2; ++mt)
#pragma unroll
        for (int nt = 0; nt < 4; ++nt) acc[mt][nt] = mfma16(af[mt], bfr[nt], acc[mt][nt]);
    }
  }
}

// ------------- fused prologue prep: enc (1024 blks) + wpeT (16) + pm4 (128)
__global__ __launch_bounds__(256) void k_prep(const float* __restrict__ pm,
                                              const float* __restrict__ wpeW,
                                              ushort* __restrict__ encb,
                                              ushort* __restrict__ wpeT,
                                              float4* __restrict__ pm4) {
  int id = blockIdx.x;
  int t = threadIdx.x;
  if (id < 1024) {
    int row = id * 32 + (t >> 3);
    int kb = (t & 7) * 8;
    ushort o[8];
#pragma unroll
    for (int u = 0; u < 8; ++u) {
      int k = kb + u;
      float val = 0.f;
      if (k < 60) {
        int c = k / 20, jj = k % 20;
        float f = (float)(1 << (jj % 10));
        float a = pm[(size_t)row * 3 + c] * f;
        val = (jj < 10) ? sinf(a) : cosf(a);
      }
      o[u] = f2b(val);
    }
    *(u32x4*)(encb + (size_t)row * 64 + kb) = *(const u32x4*)o;
  } else if (id < 1040) {
    int n = (id - 1024) * 16 + (t >> 4);
    int k = (t & 15) * 4;
    ushort o[4];
#pragma unroll
    for (int u = 0; u < 4; ++u) {
      int kk = k + u;
      o[u] = (kk < 60) ? f2b(wpeW[(size_t)kk * DD + n]) : (ushort)0;
    }
    *(u32x2*)(wpeT + (size_t)n * 64 + k) = *(const u32x2*)o;
  } else {
    int i = (id - 1040) * 256 + t;
    float x = pm[(size_t)i * 3 + 0];
    float y = pm[(size_t)i * 3 + 1];
    float z = pm[(size_t)i * 3 + 2];
    float4 v;
    v.x = x; v.y = y; v.z = z; v.w = x * x + y * y + z * z;
    pm4[i] = v;
  }
}

// -------------------------- memb = bf16(enc@wpeW + wpeb + img) via MFMA, grid (256,4)
__global__ __launch_bounds__(256) void k_gemm_mem(const ushort* __restrict__ encb,
                                                  const ushort* __restrict__ wpeT,
                                                  const float* __restrict__ wpeb,
                                                  const float* __restrict__ img,
                                                  ushort* __restrict__ memb) {
  __shared__ __align__(16) char AsB[16384];
  __shared__ __align__(16) char BsB[8192];
  int m0 = blockIdx.x * 128, n0 = blockIdx.y * 64;
  f32x4v acc[2][4] = {};
  gemm_core(encb, 64, wpeT, 64, m0, n0, 0, 64, AsB, BsB, threadIdx.x, acc);
  int t = threadIdx.x, w = t >> 6, l = t & 63, lq = l & 15, lg = l >> 4;
#pragma unroll
  for (int nt = 0; nt < 4; ++nt) {
    int n = n0 + nt * 16 + lq;
    float bv = wpeb[n];
#pragma unroll
    for (int mt = 0; mt < 2; ++mt) {
      int rowg = m0 + w * 32 + mt * 16 + lg * 4;
      f32x4v a = acc[mt][nt];
#pragma unroll
      for (int r = 0; r < 4; ++r)
        memb[(size_t)(rowg + r) * DD + n] = f2b(a[r] + bv + img[(size_t)(rowg + r) * DD + n]);
    }
  }
}

// ------------------------------- ALL weight transposes f32->bf16^T in ONE dispatch
struct T2BArgs {
  const float* fam[8];
  const float* single[5];  // tpW,tWq,tWk,tWv,tWo
  const float* fW1; const float* fW2;
  ushort* wT; ushort* w1T; ushort* w2T;
};
__global__ __launch_bounds__(256) void k_t2b_all(T2BArgs a) {
  __shared__ ushort T[64][72];
  int id = blockIdx.x;
  const float* src; ushort* dst; int K, N, k0, n0;
  if (id < 768) {
    int fam = id / 96, rem = id % 96, mi = rem >> 4, ti = rem & 15;
    src = a.fam[fam] + (size_t)mi * D2;
    dst = a.wT + (size_t)(fam * 6 + mi) * D2;
    K = DD; N = DD; k0 = (ti >> 2) * 64; n0 = (ti & 3) * 64;
  } else if (id < 848) {
    int j = (id - 768) >> 4, ti = (id - 768) & 15;
    src = a.single[j];
    dst = a.wT + (size_t)(48 + j) * D2;
    K = DD; N = DD; k0 = (ti >> 2) * 64; n0 = (ti & 3) * 64;
  } else if (id < 1616) {
    int t2 = id - 848, mi = t2 >> 7, ti = t2 & 127;
    src = a.fW1 + (size_t)mi * DD * FFD;
    dst = a.w1T + (size_t)mi * DD * FFD;
    K = DD; N = FFD; k0 = (ti >> 5) * 64; n0 = (ti & 31) * 64;
  } else {
    int t2 = id - 1616, mi = t2 >> 7, ti = t2 & 127;
    src = a.fW2 + (size_t)mi * DD * FFD;
    dst = a.w2T + (size_t)mi * DD * FFD;
    K = FFD; N = DD; k0 = (ti >> 2) * 64; n0 = (ti & 3) * 64;
  }
  int t = threadIdx.x;
  int kk = t >> 4, nn4 = (t & 15) * 4;
#pragma unroll
  for (int p = 0; p < 4; ++p) {
    int krow = kk + p * 16;
    float4 v = *(const float4*)(src + (size_t)(k0 + krow) * N + n0 + nn4);
    T[nn4 + 0][krow] = f2b(v.x);
    T[nn4 + 1][krow] = f2b(v.y);
    T[nn4 + 2][krow] = f2b(v.z);
    T[nn4 + 3][krow] = f2b(v.w);
  }
  __syncthreads();
  int nn = t >> 3, kk8 = (t & 7) * 8;
#pragma unroll
  for (int p = 0; p < 2; ++p) {
    int nrow = nn + p * 32;
    u32x4 v = *(const u32x4*)(&T[nrow][kk8]);
    *(u32x4*)(dst + (size_t)(n0 + nrow) * K + k0 + kk8) = v;
  }
}

// ------------------------------------------------------------ flat f32 -> bf16
__global__ __launch_bounds__(256) void k_f2b(const float* __restrict__ in,
                                             ushort* __restrict__ out, int n) {
  int i = (blockIdx.x * 256 + threadIdx.x) * 4;
  if (i + 3 < n) {
    float4 v = *(const float4*)(in + i);
    out[i + 0] = f2b(v.x);
    out[i + 1] = f2b(v.y);
    out[i + 2] = f2b(v.z);
    out[i + 3] = f2b(v.w);
  }
}

// ------ generic MFMA GEMM (K=256, BK=128): OM 0=f32, 1=bf16, 2=bf16+relu, 3=bf16*C1S
template <int OM>
__global__ __launch_bounds__(256) void k_gemm_gen(const ushort* __restrict__ A,
                                                  const ushort* __restrict__ Bt,
                                                  const float* __restrict__ bias,
                                                  void* __restrict__ C, int Nc) {
  __shared__ __align__(16) char AsB[32768];
  __shared__ __align__(16) char BsB[16384];
  int m0 = blockIdx.x * 128, n0 = blockIdx.y * 64;
  f32x4v acc[2][4] = {};
  gemm_core128(A, 256, Bt, 256, m0, n0, 0, 256, AsB, BsB, threadIdx.x, acc);
  int t = threadIdx.x, w = t >> 6, l = t & 63, lq = l & 15, lg = l >> 4;
#pragma unroll
  for (int nt = 0; nt < 4; ++nt) {
    int n = n0 + nt * 16 + lq;
    float bv = bias[n];
#pragma unroll
    for (int mt = 0; mt < 2; ++mt) {
      int rowg = m0 + w * 32 + mt * 16 + lg * 4;
      f32x4v a = acc[mt][nt];
      a[0] += bv; a[1] += bv; a[2] += bv; a[3] += bv;
      if (OM == 2) {
        a[0] = fmaxf(a[0], 0.f); a[1] = fmaxf(a[1], 0.f);
        a[2] = fmaxf(a[2], 0.f); a[3] = fmaxf(a[3], 0.f);
      }
      if (OM == 3) { a[0] *= C1S; a[1] *= C1S; a[2] *= C1S; a[3] *= C1S; }
      if (OM == 0) {
        float* Cf = (float*)C;
#pragma unroll
        for (int r = 0; r < 4; ++r) Cf[(size_t)(rowg + r) * Nc + n] = a[r];
      } else {
        ushort* Cb = (ushort*)C;
#pragma unroll
        for (int r = 0; r < 4; ++r) Cb[(size_t)(rowg + r) * Nc + n] = f2b(a[r]);
      }
    }
  }
}

// ------ dual-output GEMM: text K and V projections in one dispatch, grid (2, 8)
__global__ __launch_bounds__(256) void k_gemm_dual(const ushort* __restrict__ A,
                                                   const ushort* __restrict__ Bt0,
                                                   const ushort* __restrict__ Bt1,
                                                   const float* __restrict__ b0,
                                                   const float* __restrict__ b1,
                                                   float* __restrict__ C0,
                                                   float* __restrict__ C1) {
  __shared__ __align__(16) char AsB[32768];
  __shared__ __align__(16) char BsB[16384];
  int sel = blockIdx.y >> 2;
  int n0 = (blockIdx.y & 3) * 64;
  int m0 = blockIdx.x * 128;
  const ushort* Bt = sel ? Bt1 : Bt0;
  const float* bias = sel ? b1 : b0;
  float* C = sel ? C1 : C0;
  f32x4v acc[2][4] = {};
  gemm_core128(A, 256, Bt, 256, m0, n0, 0, 256, AsB, BsB, threadIdx.x, acc);
  int t = threadIdx.x, w = t >> 6, l = t & 63, lq = l & 15, lg = l >> 4;
#pragma unroll
  for (int nt = 0; nt < 4; ++nt) {
    int n = n0 + nt * 16 + lq;
    float bv = bias[n];
#pragma unroll
    for (int mt = 0; mt < 2; ++mt) {
      int rowg = m0 + w * 32 + mt * 16 + lg * 4;
      f32x4v a = acc[mt][nt];
#pragma unroll
      for (int r = 0; r < 4; ++r) C[(size_t)(rowg + r) * DD + n] = a[r] + bv;
    }
  }
}

// ===== merged self-QKV projection + cross K/V projection, one dispatch, grid 1108 =====
__global__ __launch_bounds__(256) void k_qkv_kv(
    const ushort* __restrict__ xbA, const ushort* __restrict__ Bq,
    const ushort* __restrict__ Bk, const ushort* __restrict__ Bv,
    const float* __restrict__ bq, const float* __restrict__ bk,
    const float* __restrict__ bv, ushort* __restrict__ Qb,
    ushort* __restrict__ Kbs, ushort* __restrict__ Vst,
    const ushort* __restrict__ memb, const ushort* __restrict__ Btk,
    const ushort* __restrict__ Btv, const float* __restrict__ cbk,
    const float* __restrict__ cbv, ushort* __restrict__ Kb,
    ushort* __restrict__ Vt) {
  __shared__ __align__(16) char LB[65536];
  int bid = blockIdx.x;
  int t = threadIdx.x, w = t >> 6, l = t & 63, lq = l & 15, lg = l >> 4;
  if (bid < 84) {
    char* AsB = LB;
    char* BsB = LB + 32768;
    int m0 = (bid % 7) * 128;
    int yy = bid / 7;
    int sel = yy >> 2;
    int n0 = (yy & 3) * 64;
    const ushort* Bt = sel == 0 ? Bq : (sel == 1 ? Bk : Bv);
    const float* bias = sel == 0 ? bq : (sel == 1 ? bk : bv);
    f32x4v acc[2][4] = {};
    gemm_core128(xbA, 256, Bt, 256, m0, n0, 0, 256, AsB, BsB, t, acc);
#pragma unroll
    for (int nt = 0; nt < 4; ++nt) {
      int n = n0 + nt * 16 + lq;
      float bvv = bias[n];
#pragma unroll
      for (int mt = 0; mt < 2; ++mt) {
        int rowg = m0 + w * 32 + mt * 16 + lg * 4;
        f32x4v a = acc[mt][nt];
        a[0] += bvv; a[1] += bvv; a[2] += bvv; a[3] += bvv;
        if (sel == 0) {
#pragma unroll
          for (int r = 0; r < 4; ++r) Qb[(size_t)(rowg + r) * DD + n] = f2b(a[r] * C1S);
        } else if (sel == 1) {
#pragma unroll
          for (int r = 0; r < 4; ++r) Kbs[(size_t)(rowg + r) * DD + n] = f2b(a[r]);
        } else {
          int h = n >> 5, dd = n & 31;
#pragma unroll
          for (int r = 0; r < 4; ++r) {
            int rg = rowg + r;
            if (rg < MM) {
              int b = rg / TT, tq = rg % TT;
              Vst[((size_t)((b * 8 + h) * 32 + dd)) * 128 + tq] = f2b(a[r]);
            }
          }
        }
      }
    }
  } else {
    char* AsB = LB;
    char* BsB = LB + 32768;
    int tile = bid - 84;
    int m0 = (tile & 255) * 128;
    int yy = tile >> 8;
    int isV = yy >= 2;
    int n0 = (yy & 1) * 128;
    const ushort* Bt = isV ? Btv : Btk;
    f32x4v acc[2][8] = {};
    for (int k0 = 0; k0 < 256; k0 += 128) {
      __syncthreads();
      stage2<128>(memb, 256, m0, k0, AsB, w, l);
      stage2<128>(Bt, 256, n0, k0, BsB, w, l);
      __syncthreads();
#pragma unroll
      for (int ks = 0; ks < 4; ++ks) {
        int kb = ks * 64 + lg * 16;
        bf16x8 af[2], bfr[8];
#pragma unroll
        for (int mt = 0; mt < 2; ++mt) {
          int row = w * 32 + mt * 16 + lq;
          af[mt] = __builtin_bit_cast(
              bf16x8, *(const u32x4*)(AsB + row * 256 + (kb ^ ((row & 7) << 4))));
        }
#pragma unroll
        for (int nt = 0; nt < 8; ++nt) {
          int row = nt * 16 + lq;
          bfr[nt] = __builtin_bit_cast(
              bf16x8, *(const u32x4*)(BsB + row * 256 + (kb ^ ((row & 7) << 4))));
        }
#pragma unroll
        for (int mt = 0; mt < 2; ++mt)
#pragma unroll
          for (int nt = 0; nt < 8; ++nt) acc[mt][nt] = mfma16(af[mt], bfr[nt], acc[mt][nt]);
      }
    }
    if (!isV) {
#pragma unroll
      for (int nt = 0; nt < 8; ++nt) {
        int n = n0 + nt * 16 + lq;
        float bvv = cbk[n];
#pragma unroll
        for (int mt = 0; mt < 2; ++mt) {
          int rowg = m0 + w * 32 + mt * 16 + lg * 4;
          f32x4v a = acc[mt][nt];
#pragma unroll
          for (int r = 0; r < 4; ++r) Kb[(size_t)(rowg + r) * DD + n] = f2b(a[r] + bvv);
        }
      }
    } else {
      ushort* T = (ushort*)LB;  // [128][136]
      __syncthreads();
#pragma unroll
      for (int nt = 0; nt < 8; ++nt) {
        int ddl = nt * 16 + lq;
        float bvv = cbv[n0 + ddl];
#pragma unroll
        for (int mt = 0; mt < 2; ++mt) {
          int kl = w * 32 + mt * 16 + lg * 4;
          f32x4v a = acc[mt][nt];
          u32x2 pv;
          pv[0] = pk2(a[0] + bvv, a[1] + bvv);
          pv[1] = pk2(a[2] + bvv, a[3] + bvv);
          *(u32x2*)(T + ddl * 136 + kl) = pv;
        }
      }
      __syncthreads();
      int row = t >> 1, half = t & 1;
      int b = m0 >> 12, key0 = m0 & 4095;
      const ushort* src = T + row * 136 + half * 64;
      ushort* dst = Vt + ((size_t)(b * 256 + n0 + row)) * 4096 + key0 + half * 64;
#pragma unroll
      for (int i = 0; i < 8; ++i)
        *(u32x4*)(dst + i * 8) = *(const u32x4*)(src + i * 8);
    }
  }
}

// ------- o-proj + residual + LN fused: 64x256 tile, BK=128; grid 14.
// MERGE=1: A comes from cross partials (pacc/pl) merged into full-row swizzled LDS.
template <int MERGE, int QPROJ>
__global__ __launch_bounds__(256) void k_gemm_o_ln(
    const ushort* __restrict__ A, const float* __restrict__ pacc,
    const float* __restrict__ pl, const ushort* __restrict__ WoT,
    const float* __restrict__ bo, const float* __restrict__ xres,
    const float* __restrict__ g, const float* __restrict__ be,
    float* __restrict__ xout, ushort* __restrict__ xbout,
    const float* __restrict__ Wp, const float* __restrict__ bp,
    float* __restrict__ pqout) {
  constexpr int ABYTES = MERGE ? 32768 : 16384;
  __shared__ __align__(16) char LB[ABYTES + 65536];
  char* AsB = LB;
  char* BsB = LB + ABYTES;
  int m0 = blockIdx.x * 64;
  int t = threadIdx.x, w = t >> 6, l = t & 63, lq = l & 15, lg = l >> 4;

  if (MERGE) {
    // merge pacc/pl into full-row A: 64 rows x 512B, swizzled (XOR bits 4-6)
    int row = t >> 2, q4 = t & 3;
    int grow = m0 + row;
    int b = grow / TT, tq = grow - b * TT;
#pragma unroll
    for (int h2 = 0; h2 < 2; ++h2) {
      int h = q4 * 2 + h2;
      int bh = b * 8 + h;
      float lsum = 0.f;
#pragma unroll
      for (int kc = 0; kc < KC; ++kc) lsum += pl[(size_t)(kc * 64 + bh) * TT + tq];
      float linv = 1.f / lsum;
#pragma unroll
      for (int j8 = 0; j8 < 4; ++j8) {
        float4 s0 = {0.f, 0.f, 0.f, 0.f}, s1 = {0.f, 0.f, 0.f, 0.f};
#pragma unroll
        for (int kc = 0; kc < KC; ++kc) {
          const float4* pp =
              (const float4*)(pacc + ((size_t)(kc * 64 + bh) * TT + tq) * 32 + j8 * 8);
          float4 a0 = pp[0], a1 = pp[1];
          s0.x += a0.x; s0.y += a0.y; s0.z += a0.z; s0.w += a0.w;
          s1.x += a1.x; s1.y += a1.y; s1.z += a1.z; s1.w += a1.w;
        }
        u32x4 pv;
        pv[0] = pk2(s0.x * linv, s0.y * linv);
        pv[1] = pk2(s0.z * linv, s0.w * linv);
        pv[2] = pk2(s1.x * linv, s1.y * linv);
        pv[3] = pk2(s1.z * linv, s1.w * linv);
        int cb16 = (h * 32 + j8 * 8) * 2;  // byte offset in row
        *(u32x4*)(AsB + row * 512 + (cb16 ^ ((row & 7) << 4))) = pv;
      }
    }
  }

  f32x4v acc[16] = {};
  for (int k0 = 0; k0 < 256; k0 += 128) {
    __syncthreads();
    if (!MERGE) stage2<64>(A, 256, m0, k0, AsB, w, l);
    stage2<256>(WoT, 256, 0, k0, BsB, w, l);
    __syncthreads();
#pragma unroll
    for (int ks = 0; ks < 4; ++ks) {
      int kb = ks * 64 + lg * 16;
      int arow = w * 16 + lq;
      bf16x8 af;
      if (MERGE)
        af = __builtin_bit_cast(
            bf16x8, *(const u32x4*)(AsB + arow * 512 + ((k0 * 2 + kb) ^ ((arow & 7) << 4))));
      else
        af = __builtin_bit_cast(
            bf16x8, *(const u32x4*)(AsB + arow * 256 + (kb ^ ((arow & 7) << 4))));
#pragma unroll
      for (int nt = 0; nt < 16; ++nt) {
        int brow = nt * 16 + lq;
        bf16x8 bf = __builtin_bit_cast(
            bf16x8, *(const u32x4*)(BsB + brow * 256 + (kb ^ ((brow & 7) << 4))));
        acc[nt] = mfma16(af, bf, acc[nt]);
      }
    }
  }
  int rowb = m0 + w * 16 + lg * 4;
  float s[4] = {}, s2[4] = {};
#pragma unroll
  for (int nt = 0; nt < 16; ++nt) {
    int col = nt * 16 + lq;
    float bv = bo[col];
    f32x4v a = acc[nt];
#pragma unroll
    for (int r = 0; r < 4; ++r) {
      a[r] += bv + xres[(size_t)(rowb + r) * DD + col];
      s[r] += a[r];
      s2[r] += a[r] * a[r];
    }
    acc[nt] = a;
  }
#pragma unroll
  for (int r = 0; r < 4; ++r) {
#pragma unroll
    for (int o = 1; o < 16; o <<= 1) {
      s[r] += __shfl_xor(s[r], o, 64);
      s2[r] += __shfl_xor(s2[r], o, 64);
    }
  }
  float mu[4], inv[4];
#pragma unroll
  for (int r = 0; r < 4; ++r) {
    mu[r] = s[r] * (1.f / DD);
    float var = s2[r] * (1.f / DD) - mu[r] * mu[r];
    inv[r] = rsqrtf(var + 1e-5f);
  }
  float pp0[4] = {}, pp1[4] = {}, pp2[4] = {};
#pragma unroll
  for (int nt = 0; nt < 16; ++nt) {
    int col = nt * 16 + lq;
    float gd = g[col], bd = be[col];
    float w0 = 0.f, w1 = 0.f, w2 = 0.f;
    if (QPROJ) { w0 = Wp[col * 3]; w1 = Wp[col * 3 + 1]; w2 = Wp[col * 3 + 2]; }
#pragma unroll
    for (int r = 0; r < 4; ++r) {
      float ln = (acc[nt][r] - mu[r]) * inv[r] * gd + bd;
      xout[(size_t)(rowb + r) * DD + col] = ln;
      xbout[(size_t)(rowb + r) * DD + col] = f2b(ln);
      if (QPROJ) { pp0[r] += ln * w0; pp1[r] += ln * w1; pp2[r] += ln * w2; }
    }
  }
  if (QPROJ) {
#pragma unroll
    for (int r = 0; r < 4; ++r) {
#pragma unroll
      for (int o = 1; o < 16; o <<= 1) {
        pp0[r] += __shfl_xor(pp0[r], o, 64);
        pp1[r] += __shfl_xor(pp1[r], o, 64);
        pp2[r] += __shfl_xor(pp2[r], o, 64);
      }
      if (lq == 0) {
        pqout[(size_t)(rowb + r) * 3 + 0] = pp0[r] + bp[0];
        pqout[(size_t)(rowb + r) * 3 + 1] = pp1[r] + bp[1];
        pqout[(size_t)(rowb + r) * 3 + 2] = pp2[r] + bp[2];
      }
    }
  }
}

// -------------------------------------------- x init (f32 + bf16 mirror)
__global__ __launch_bounds__(256) void k_init_x(const float* __restrict__ qe,
                                                const float* __restrict__ pt,
                                                float* __restrict__ x,
                                                ushort* __restrict__ xb) {
  int r = blockIdx.x, d = threadIdx.x;
  int t = r % TT;
  float v = (t < NQRY) ? qe[t * DD + d] : pt[d];
  x[(size_t)r * DD + d] = v;
  xb[(size_t)r * DD + d] = f2b(v);
}

// ------------------------- text attention (32 keys), f32 in, bf16 out
__global__ __launch_bounds__(128) void k_attn_small(const float* __restrict__ q,
                                                    const float* __restrict__ k,
                                                    const float* __restrict__ v,
                                                    ushort* __restrict__ out,
                                                    int NK) {
  int bh = blockIdx.x;
  int b = bh >> 3, h = bh & 7;
  __shared__ float Ks[TT][HDIM];
  __shared__ float Vs[TT][HDIM];
  for (int i = threadIdx.x; i < NK * HDIM; i += 128) {
    int n = i >> 5, j = i & 31;
    Ks[n][j] = k[(size_t)(b * NK + n) * DD + h * HDIM + j];
    Vs[n][j] = v[(size_t)(b * NK + n) * DD + h * HDIM + j];
  }
  __syncthreads();
  int t = threadIdx.x;
  if (t >= TT) return;
  float qv[HDIM];
  const float* qp = q + (size_t)(b * TT + t) * DD + h * HDIM;
#pragma unroll
  for (int j = 0; j < HDIM; ++j) qv[j] = qp[j];
  const float sc = 0.17677669529663687f * 1.4426950408889634f;
  float l = 0.f, acc[HDIM] = {};
  for (int n = 0; n < NK; ++n) {
    float s = 0.f;
#pragma unroll
    for (int j = 0; j < HDIM; ++j) s += qv[j] * Ks[n][j];
    float p = exp2f(s * sc);
    l += p;
#pragma unroll
    for (int j = 0; j < HDIM; ++j) acc[j] += p * Vs[n][j];
  }
  float inv = 1.f / l;
  ushort* op = out + (size_t)(b * TT + t) * DD + h * HDIM;
#pragma unroll
  for (int j = 0; j < HDIM; ++j) op[j] = f2b(acc[j] * inv);
}

// ---------------- MFMA self-attention (101 keys pad 128, no bias), grid 64
__global__ __launch_bounds__(256) void k_self_mfma(const ushort* __restrict__ Qb,
                                                   const ushort* __restrict__ Kbs,
                                                   const ushort* __restrict__ Vst,
                                                   ushort* __restrict__ out) {
  int bh = blockIdx.x;
  int b = bh >> 3, h = bh & 7;
  int t = threadIdx.x, w = t >> 6, l = t & 63, lq = l & 15, lg = l >> 4;
  __shared__ ushort Plds[4][2][16][40];
  const f32x4v Z = {0.f, 0.f, 0.f, 0.f};
  bf16x8 qfb[2];
  f32x4v oacc[2][2] = {};
  float lsum[2] = {0.f, 0.f};
#pragma unroll
  for (int qi = 0; qi < 2; ++qi) {
    int qidx = (w * 2 + qi) * 16 + lq;
    int qc = qidx < TT ? qidx : TT - 1;
    qfb[qi] = __builtin_bit_cast(
        bf16x8, *(const u32x4*)(Qb + (size_t)(b * TT + qc) * DD + h * HDIM + lg * 8));
  }
  for (int kk = 0; kk < 128; kk += 32) {
    bf16x8 kf[2], vf[2];
#pragma unroll
    for (int t2 = 0; t2 < 2; ++t2) {
      int key = kk + t2 * 16 + lq;
      int kc2 = key < TT ? key : TT - 1;
      kf[t2] = __builtin_bit_cast(
          bf16x8, *(const u32x4*)(Kbs + (size_t)(b * TT + kc2) * DD + h * HDIM + lg * 8));
    }
#pragma unroll
    for (int dt = 0; dt < 2; ++dt)
      vf[dt] = __builtin_bit_cast(
          bf16x8, *(const u32x4*)(Vst + (size_t)(bh * 32 + dt * 16 + lq) * 128 + kk + lg * 8));
#pragma unroll
    for (int qi = 0; qi < 2; ++qi) {
      f32x4v s0 = mfma16(kf[0], qfb[qi], Z);
      f32x4v s1 = mfma16(kf[1], qfb[qi], Z);
      float p[2][4];
#pragma unroll
      for (int t2 = 0; t2 < 2; ++t2) {
#pragma unroll
        for (int r = 0; r < 4; ++r) {
          int kr = kk + t2 * 16 + lg * 4 + r;
          float sv = (t2 == 0) ? s0[r] : s1[r];
          p[t2][r] = (kr < TT) ? exp2f(sv) : 0.f;
        }
        lsum[qi] += (p[t2][0] + p[t2][1]) + (p[t2][2] + p[t2][3]);
      }
      u32x2 w0, w1;
      w0[0] = pk2(p[0][0], p[0][1]);
      w0[1] = pk2(p[0][2], p[0][3]);
      w1[0] = pk2(p[1][0], p[1][1]);
      w1[1] = pk2(p[1][2], p[1][3]);
      *(u32x2*)(&Plds[w][qi][lq][lg * 4]) = w0;
      *(u32x2*)(&Plds[w][qi][lq][16 + lg * 4]) = w1;
      bf16x8 pf = __builtin_bit_cast(bf16x8, *(const u32x4*)(&Plds[w][qi][lq][lg * 8]));
      oacc[qi][0] = mfma16(vf[0], pf, oacc[qi][0]);
      oacc[qi][1] = mfma16(vf[1], pf, oacc[qi][1]);
    }
  }
#pragma unroll
  for (int qi = 0; qi < 2; ++qi) {
    float lv = lsum[qi];
    lv += __shfl_xor(lv, 16, 64);
    lv += __shfl_xor(lv, 32, 64);
    float inv = 1.f / lv;
    int qidx = (w * 2 + qi) * 16 + lq;
    if (qidx < TT) {
      ushort* op = out + (size_t)(b * TT + qidx) * DD + h * HDIM;
#pragma unroll
      for (int dt = 0; dt < 2; ++dt)
#pragma unroll
        for (int r = 0; r < 4; ++r)
          op[dt * 16 + lg * 4 + r] = f2b(oacc[qi][dt][r] * inv);
    }
  }
}

// ----------------------- FFN2 split-K: partials P[z][row][col], grid (7, 4, 8), BK=128
__global__ __launch_bounds__(256) void k_ffn2sk(const ushort* __restrict__ A,
                                                const ushort* __restrict__ Bt,
                                                float* __restrict__ P) {
  __shared__ __align__(16) char AsB[32768];
  __shared__ __align__(16) char BsB[16384];
  int m0 = blockIdx.x * 128, n0 = blockIdx.y * 64, z = blockIdx.z;
  f32x4v acc[2][4] = {};
  gemm_core128(A, FFD, Bt, FFD, m0, n0, z * 256, z * 256 + 256, AsB, BsB, threadIdx.x, acc);
  int t = threadIdx.x, w = t >> 6, l = t & 63, lq = l & 15, lg = l >> 4;
#pragma unroll
  for (int nt = 0; nt < 4; ++nt) {
    int n = n0 + nt * 16 + lq;
#pragma unroll
    for (int mt = 0; mt < 2; ++mt) {
      int rowg = m0 + w * 32 + mt * 16 + lg * 4;
      f32x4v a = acc[mt][nt];
#pragma unroll
      for (int r = 0; r < 4; ++r)
        P[((size_t)z * MMP + rowg + r) * DD + n] = a[r];
    }
  }
}

// -------------------- FFN2 reduce + bias + residual + LN3 -> x, xb
__global__ __launch_bounds__(256) void k_red_ln3(const float* __restrict__ P,
                                                 const float* __restrict__ bias,
                                                 const float* __restrict__ xres,
                                                 const float* __restrict__ g,
                                                 const float* __restrict__ be,
                                                 float* __restrict__ xout,
                                                 ushort* __restrict__ xbout) {
  int row = blockIdx.x, d = threadIdx.x;
  float a = xres[(size_t)row * DD + d] + bias[d];
#pragma unroll
  for (int z = 0; z < 8; ++z) a += P[((size_t)z * MMP + row) * DD + d];
  float s = a, s2 = a * a;
#pragma unroll
  for (int o = 1; o < 64; o <<= 1) {
    s += __shfl_xor(s, o, 64);
    s2 += __shfl_xor(s2, o, 64);
  }
  __shared__ float ws[4], ws2[4];
  int wid = d >> 6;
  if ((d & 63) == 0) { ws[wid] = s; ws2[wid] = s2; }
  __syncthreads();
  s = ws[0] + ws[1] + ws[2] + ws[3];
  s2 = ws2[0] + ws2[1] + ws2[2] + ws2[3];
  float m = s * (1.f / DD);
  float var = s2 * (1.f / DD) - m * m;
  float inv = rsqrtf(var + 1e-5f);
  float r_ = (a - m) * inv * g[d] + be[d];
  xout[(size_t)row * DD + d] = r_;
  xbout[(size_t)row * DD + d] = f2b(r_);
}

// ------------------- MFMA flash cross-attention with distance bias (q pre-scaled bf16)
__global__ __launch_bounds__(256) void k_cross_mfma(
    const ushort* __restrict__ Qb, const ushort* __restrict__ Kb,
    const ushort* __restrict__ Vt, const float* __restrict__ posq,
    const float4* __restrict__ pm4, const float* __restrict__ betaL,
    float* __restrict__ pacc, float* __restrict__ pl) {
  int bh = blockIdx.x, kc = blockIdx.y;
  int b = bh >> 3, h = bh & 7;
  int t = threadIdx.x, w = t >> 6, l = t & 63, lq = l & 15, lg = l >> 4;
  const float L2E = 1.4426950408889634f;
  float spb = log1pf(expf(betaL[h]));
  float cb = spb * L2E;

  __shared__ float4 pm4s[KPC];
  __shared__ ushort Plds[4][2][16][40];

  int kbase = b * NN + kc * KPC;
  for (int i = t; i < KPC; i += 256) pm4s[i] = pm4[kbase + i];
  __syncthreads();

  const f32x4v Z = {0.f, 0.f, 0.f, 0.f};
  bf16x8 qfb[2];
  float a0[2], px[2], py[2], pz[2];
  f32x4v oacc[2][2] = {};
  float lsum[2] = {0.f, 0.f};

#pragma unroll
  for (int qi = 0; qi < 2; ++qi) {
    int qt = w * 2 + qi;
    int qidx = qt * 16 + lq;
    int qc = qidx < TT ? qidx : TT - 1;
    size_t xr = (size_t)(b * TT + qc);
    qfb[qi] = __builtin_bit_cast(
        bf16x8, *(const u32x4*)(Qb + xr * 256 + h * 32 + lg * 8));
    float qx = posq[xr * 3 + 0], qy = posq[xr * 3 + 1], qz = posq[xr * 3 + 2];
    a0[qi] = -cb * (qx * qx + qy * qy + qz * qz);
    px[qi] = 2.f * cb * qx;
    py[qi] = 2.f * cb * qy;
    pz[qi] = 2.f * cb * qz;
  }

  for (int kk = 0; kk < KPC; kk += 32) {
    bf16x8 kf[2], vf[2];
#pragma unroll
    for (int t2 = 0; t2 < 2; ++t2)
      kf[t2] = __builtin_bit_cast(
          bf16x8, *(const u32x4*)(Kb + (size_t)(kbase + kk + t2 * 16 + lq) * 256 +
                                  h * 32 + lg * 8));
#pragma unroll
    for (int dt = 0; dt < 2; ++dt)
      vf[dt] = __builtin_bit_cast(
          bf16x8, *(const u32x4*)(Vt + (size_t)(bh * 32 + dt * 16 + lq) * 4096 +
                                  kc * KPC + kk + lg * 8));
    float bx[2][4], by[2][4], bz[2][4], b0[2][4];
#pragma unroll
    for (int t2 = 0; t2 < 2; ++t2)
#pragma unroll
      for (int r = 0; r < 4; ++r) {
        float4 pv = pm4s[kk + t2 * 16 + lg * 4 + r];
        bx[t2][r] = pv.x; by[t2][r] = pv.y; bz[t2][r] = pv.z;
        b0[t2][r] = cb * pv.w;
      }
#pragma unroll
    for (int qi = 0; qi < 2; ++qi) {
      f32x4v s0 = mfma16(kf[0], qfb[qi], Z);
      f32x4v s1 = mfma16(kf[1], qfb[qi], Z);
      float p[2][4];
#pragma unroll
      for (int t2 = 0; t2 < 2; ++t2) {
#pragma unroll
        for (int r = 0; r < 4; ++r) {
          float sv = (t2 == 0) ? s0[r] : s1[r];
          float bias = fmaf(px[qi], bx[t2][r],
                       fmaf(py[qi], by[t2][r],
                       fmaf(pz[qi], bz[t2][r], a0[qi] - b0[t2][r])));
          p[t2][r] = exp2f(sv + bias);
        }
        lsum[qi] += (p[t2][0] + p[t2][1]) + (p[t2][2] + p[t2][3]);
      }
      u32x2 w0, w1;
      w0[0] = pk2(p[0][0], p[0][1]);
      w0[1] = pk2(p[0][2], p[0][3]);
      w1[0] = pk2(p[1][0], p[1][1]);
      w1[1] = pk2(p[1][2], p[1][3]);
      *(u32x2*)(&Plds[w][qi][lq][lg * 4]) = w0;
      *(u32x2*)(&Plds[w][qi][lq][16 + lg * 4]) = w1;
      bf16x8 pf = __builtin_bit_cast(bf16x8, *(const u32x4*)(&Plds[w][qi][lq][lg * 8]));
      oacc[qi][0] = mfma16(vf[0], pf, oacc[qi][0]);
      oacc[qi][1] = mfma16(vf[1], pf, oacc[qi][1]);
    }
  }

#pragma unroll
  for (int qi = 0; qi < 2; ++qi) {
    float lv = lsum[qi];
    lv += __shfl_xor(lv, 16, 64);
    lv += __shfl_xor(lv, 32, 64);
    int qt = w * 2 + qi;
    int qidx = qt * 16 + lq;
    if (qidx < TT) {
      size_t o = ((size_t)(kc * 64 + bh) * TT + qidx) * 32;
#pragma unroll
      for (int dt = 0; dt < 2; ++dt) {
        f32x4v a = oacc[qi][dt];
        float4 st;
        st.x = a[0]; st.y = a[1]; st.z = a[2]; st.w = a[3];
        *(float4*)(pacc + o + dt * 16 + lg * 4) = st;
      }
      if (lg == 0) pl[(size_t)(kc * 64 + bh) * TT + qidx] = lv;
    }
  }
}

// ------------------------ final LN + scatter to hs / pres
__global__ __launch_bounds__(256) void k_fin(const float* __restrict__ x,
                                             const float* __restrict__ g,
                                             const float* __restrict__ be,
                                             float* __restrict__ hs,
                                             float* __restrict__ pres) {
  int row = blockIdx.x, d = threadIdx.x;
  int b = row / TT, tq = row % TT;
  float v = x[(size_t)row * DD + d];
  float s = v, s2 = v * v;
#pragma unroll
  for (int o = 1; o < 64; o <<= 1) {
    s += __shfl_xor(s, o, 64);
    s2 += __shfl_xor(s2, o, 64);
  }
  __shared__ float ws[4], ws2[4];
  int wid = d >> 6;
  if ((d & 63) == 0) { ws[wid] = s; ws2[wid] = s2; }
  __syncthreads();
  s = ws[0] + ws[1] + ws[2] + ws[3];
  s2 = ws2[0] + ws2[1] + ws2[2] + ws2[3];
  float m = s * (1.f / DD);
  float var = s2 * (1.f / DD) - m * m;
  float inv = rsqrtf(var + 1e-5f);
  float r = (v - m) * inv * g[d] + be[d];
  if (tq < NQRY) hs[((size_t)(b * NQRY + tq)) * DD + d] = r;
  else pres[(size_t)b * DD + d] = r;
}

// ----------------------- parallel presence-MLP stage: out[8][256] = relu(in@W + b)
__global__ __launch_bounds__(256) void k_mlp8(const float* __restrict__ in,
                                              const float* __restrict__ W,
                                              const float* __restrict__ b,
                                              float* __restrict__ out) {
  __shared__ float ins[8][DD];
  __shared__ float red[8][32][8];  // [ks][c][r]
  int t = threadIdx.x;
  for (int i = t; i < 8 * DD; i += 256) ins[i >> 8][i & 255] = in[i];
  __syncthreads();
  int c = t & 31, ks = t >> 5;
  int cg = blockIdx.x * 32 + c;
  float acc[8] = {};
  for (int k = ks * 32; k < ks * 32 + 32; ++k) {
    float w = W[(size_t)k * DD + cg];
#pragma unroll
    for (int r = 0; r < 8; ++r) acc[r] += ins[r][k] * w;
  }
#pragma unroll
  for (int r = 0; r < 8; ++r) red[ks][c][r] = acc[r];
  __syncthreads();
  int c2 = t & 31, r2 = t >> 5;
  float s = 0.f;
#pragma unroll
  for (int k2 = 0; k2 < 8; ++k2) s += red[k2][c2][r2];
  s = fmaxf(s + b[blockIdx.x * 32 + c2], 0.f);
  out[(size_t)r2 * DD + blockIdx.x * 32 + c2] = s;
}

__global__ __launch_bounds__(256) void k_logit(const float* __restrict__ h2,
                                               const float* __restrict__ W3,
                                               const float* __restrict__ b3,
                                               float* __restrict__ out) {
  int r = threadIdx.x >> 5, lane = threadIdx.x & 31;
  float s = 0.f;
  for (int k = lane; k < DD; k += 32) s += h2[r * DD + k] * W3[k];
#pragma unroll
  for (int o = 16; o; o >>= 1) s += __shfl_xor(s, o, 32);
  if (lane == 0) out[r] = s + b3[0];
}

// =======================================================================================
extern "C" void kernel_launch(void* const* d_in, const int* in_sizes, int n_in,
                              void* d_out, int out_size, void* d_ws, size_t ws_size,
                              hipStream_t stream) {
  (void)in_sizes; (void)n_in; (void)out_size; (void)ws_size;
  auto F = [&](int i) { return (const float*)d_in[i]; };
  const float* img   = F(0);
  const float* txtf  = F(1);
  const float* pm    = F(2);
  const float* qe    = F(3);
  const float* ptok  = F(4);
  const float* tpW   = F(5);
  const float* tpb   = F(6);
  const float* tWq   = F(7);  const float* tbq = F(8);
  const float* tWk   = F(9);  const float* tbk = F(10);
  const float* tWv   = F(11); const float* tbv = F(12);
  const float* tWo   = F(13); const float* tbo = F(14);
  const float* tlng  = F(15); const float* tlnb = F(16);
  const float* wpeW  = F(17); const float* wpeb = F(18);
  const float* saWq  = F(19); const float* sabq = F(20);
  const float* saWk  = F(21); const float* sabk = F(22);
  const float* saWv  = F(23); const float* sabv = F(24);
  const float* saWo  = F(25); const float* sabo = F(26);
  const float* caWq  = F(27); const float* cabq = F(28);
  const float* caWk  = F(29); const float* cabk = F(30);
  const float* caWv  = F(31); const float* cabv = F(32);
  const float* caWo  = F(33); const float* cabo = F(34);
  const float* fW1   = F(35); const float* fb1 = F(36);
  const float* fW2   = F(37); const float* fb2 = F(38);
  const float* ln1g  = F(39); const float* ln1b = F(40);
  const float* ln2g  = F(41); const float* ln2b = F(42);
  const float* ln3g  = F(43); const float* ln3b = F(44);
  const float* posW  = F(45); const float* posb = F(46);
  const float* beta  = F(47);
  const float* fing  = F(48); const float* finb = F(49);
  const float* pW1   = F(50); const float* pb1 = F(51);
  const float* pW2   = F(52); const float* pb2 = F(53);
  const float* pW3   = F(54); const float* pb3 = F(55);

  char* wp = (char*)d_ws;
  auto alloc = [&](size_t bytes) {
    char* p = wp;
    wp += (bytes + 255) & ~(size_t)255;
    return (void*)p;
  };
  ushort* memb = (ushort*)alloc((size_t)BNN * DD * 2);
  ushort* Kb   = (ushort*)alloc((size_t)BNN * DD * 2);
  ushort* Vt   = (ushort*)alloc((size_t)64 * 32 * 4096 * 2);
  ushort* encb = (ushort*)alloc((size_t)BNN * 64 * 2);
  ushort* wT   = (ushort*)alloc((size_t)53 * D2 * 2);
  ushort* w1T  = (ushort*)alloc((size_t)6 * FFD * DD * 2);
  ushort* w2T  = (ushort*)alloc((size_t)6 * DD * FFD * 2);
  ushort* xb   = (ushort*)alloc((size_t)MMP * DD * 2);
  ushort* hb   = (ushort*)alloc((size_t)MMP * FFD * 2);
  ushort* tDb  = (ushort*)alloc((size_t)MMP * DD * 2);
  ushort* tQb  = (ushort*)alloc((size_t)MMP * DD * 2);
  ushort* tKb  = (ushort*)alloc((size_t)MMP * DD * 2);
  ushort* tQb2 = (ushort*)alloc((size_t)MMP * DD * 2);
  ushort* Vst  = (ushort*)alloc((size_t)64 * 32 * 128 * 2);
  ushort* txtb = (ushort*)alloc((size_t)BB * NTXT * DD * 2);
  ushort* txtb2= (ushort*)alloc((size_t)BB * NTXT * DD * 2);
  float* fp2  = (float*)alloc((size_t)8 * MMP * DD * 4);
  float* x    = (float*)alloc((size_t)MMP * DD * 4);
  float* tA   = (float*)alloc((size_t)MMP * DD * 4);
  float* tK   = (float*)alloc((size_t)BB * NTXT * DD * 4);
  float* tV   = (float*)alloc((size_t)BB * NTXT * DD * 4);
  float* pacc = (float*)alloc((size_t)(KC * 64 + 8) * TT * HDIM * 4);
  float* pl   = (float*)alloc((size_t)(KC * 64 + 8) * TT * 4);
  float* posq = (float*)alloc((size_t)4096 * 4);
  float4* pm4 = (float4*)alloc((size_t)BNN * 16);
  float* pres = (float*)alloc((size_t)BB * DD * 4);
  float* ph1  = (float*)alloc((size_t)BB * DD * 4);
  float* ph2  = (float*)alloc((size_t)BB * DD * 4);
  ushort* wpeT = (ushort*)alloc((size_t)DD * 64 * 2);

  // ---- prologue
  k_prep<<<1168, 256, 0, stream>>>(pm, wpeW, encb, wpeT, pm4);
  T2BArgs ta;
  ta.fam[0] = saWq; ta.fam[1] = saWk; ta.fam[2] = saWv; ta.fam[3] = saWo;
  ta.fam[4] = caWq; ta.fam[5] = caWk; ta.fam[6] = caWv; ta.fam[7] = caWo;
  ta.single[0] = tpW; ta.single[1] = tWq; ta.single[2] = tWk;
  ta.single[3] = tWv; ta.single[4] = tWo;
  ta.fW1 = fW1; ta.fW2 = fW2; ta.wT = wT; ta.w1T = w1T; ta.w2T = w2T;
  k_t2b_all<<<2384, 256, 0, stream>>>(ta);
  k_gemm_mem<<<dim3(256, 4), 256, 0, stream>>>(encb, wpeT, wpeb, img, memb);

  // ---- phase 0: text block
  k_f2b<<<(BB * NTXT * DD) / 1024, 256, 0, stream>>>(txtf, txtb, BB * NTXT * DD);
  k_gemm_gen<1><<<dim3(2, 4), 256, 0, stream>>>(txtb, wT + (size_t)48 * D2, tpb, txtb2, DD);
  k_gemm_dual<<<dim3(2, 8), 256, 0, stream>>>(txtb2, wT + (size_t)50 * D2,
                                              wT + (size_t)51 * D2, tbk, tbv, tK, tV);
  k_init_x<<<MM, 256, 0, stream>>>(qe, ptok, x, xb);
  k_gemm_gen<0><<<dim3(7, 4), 256, 0, stream>>>(xb, wT + (size_t)49 * D2, tbq, tA, DD);
  k_attn_small<<<64, 128, 0, stream>>>(tA, tK, tV, tDb, NTXT);
  k_gemm_o_ln<0, 0><<<14, 256, 0, stream>>>(tDb, nullptr, nullptr, wT + (size_t)52 * D2,
                                            tbo, x, tlng, tlnb, x, xb,
                                            nullptr, nullptr, nullptr);

  for (int i = 0; i < NLAY; ++i) {
    int iD = i * DD;
    // self-QKV (84 blocks) + cross-K/V of memb (1024 blocks) co-dispatched
    k_qkv_kv<<<1108, 256, 0, stream>>>(
        xb, wT + (size_t)(0 + i) * D2, wT + (size_t)(6 + i) * D2, wT + (size_t)(12 + i) * D2,
        sabq + iD, sabk + iD, sabv + iD, tQb, tKb, Vst,
        memb, wT + (size_t)(30 + i) * D2, wT + (size_t)(36 + i) * D2,
        cabk + iD, cabv + iD, Kb, Vt);
    k_self_mfma<<<64, 256, 0, stream>>>(tQb, tKb, Vst, tDb);
    // o-proj + LN1 + posq
    k_gemm_o_ln<0, 1><<<14, 256, 0, stream>>>(tDb, nullptr, nullptr,
                                              wT + (size_t)(18 + i) * D2, sabo + iD,
                                              x, ln1g + iD, ln1b + iD, x, xb,
                                              posW + (size_t)i * DD * 3, posb + i * 3, posq);
    // cross-q projection (scaled bf16)
    k_gemm_gen<3><<<dim3(7, 4), 256, 0, stream>>>(xb, wT + (size_t)(24 + i) * D2,
                                                  cabq + iD, tQb2, DD);
    k_cross_mfma<<<dim3(64, KC), 256, 0, stream>>>(tQb2, Kb, Vt, posq, pm4,
                                                   beta + i * NH, pacc, pl);
    // merged cross-merge + o-proj + LN2
    k_gemm_o_ln<1, 0><<<14, 256, 0, stream>>>(nullptr, pacc, pl,
                                              wT + (size_t)(42 + i) * D2, cabo + iD,
                                              x, ln2g + iD, ln2b + iD, x, xb,
                                              nullptr, nullptr, nullptr);
    // FFN
    k_gemm_gen<2><<<dim3(7, 32), 256, 0, stream>>>(xb, w1T + (size_t)i * DD * FFD,
                                                   fb1 + i * FFD, hb, FFD);
    k_ffn2sk<<<dim3(7, 4, 8), 256, 0, stream>>>(hb, w2T + (size_t)i * DD * FFD, fp2);
    k_red_ln3<<<MM, 256, 0, stream>>>(fp2, fb2 + iD, x, ln3g + iD, ln3b + iD, x, xb);
  }

  // ---- epilogue
  k_fin<<<MM, 256, 0, stream>>>(x, fing, finb, (float*)d_out, pres);
  k_mlp8<<<8, 256, 0, stream>>>(pres, pW1, pb1, ph1);
  k_mlp8<<<8, 256, 0, stream>>>(ph1, pW2, pb2, ph2);
  k_logit<<<1, 256, 0, stream>>>(ph2, pW3, pb3, (float*)d_out + (size_t)BB * NQRY * DD);
}

// Round 13
// 690.050 us; speedup vs baseline: 1.1400x; 1.1400x over previous
//
#include <hip/hip_runtime.h>
#include <math.h>

#define DD 256
#define NH 8
#define HDIM 32
#define NLAY 6
#define NQRY 100
#define TT 101
#define BB 8
#define NN 4096
#define NTXT 32
#define FFD 2048
#define MM (BB*TT)      // 808
#define MMP 896
#define BNN (BB*NN)     // 32768
#define KC 8
#define KPC (NN/KC)     // 512
#define D2 (DD*DD)
#define C1S 0.25506807170842403f   // (1/sqrt(32)) * log2(e)

typedef __bf16 bf16x8 __attribute__((ext_vector_type(8)));
typedef float f32x4v __attribute__((ext_vector_type(4)));
typedef unsigned int u32x4 __attribute__((ext_vector_type(4)));
typedef unsigned int u32x2 __attribute__((ext_vector_type(2)));

__device__ __forceinline__ ushort f2b(float f) {
  unsigned u = __builtin_bit_cast(unsigned, f);
  u += 0x7FFF + ((u >> 16) & 1);
  return (ushort)(u >> 16);
}
__device__ __forceinline__ unsigned pk2(float lo, float hi) {
  return (unsigned)f2b(lo) | ((unsigned)f2b(hi) << 16);
}
__device__ __forceinline__ f32x4v mfma16(bf16x8 a, bf16x8 b, f32x4v c) {
  return __builtin_amdgcn_mfma_f32_16x16x32_bf16(a, b, c, 0, 0, 0);
}

// ---- async global->LDS 16B, wave-uniform LDS base + lane*16 ----
__device__ __forceinline__ void gload16(const void* g, void* l) {
  __builtin_amdgcn_global_load_lds(
      (const __attribute__((address_space(1))) void*)g,
      (__attribute__((address_space(3))) void*)l, 16, 0, 0);
}

// ---- BK=64 stage: NROWS x 128B rows, XOR-16B swizzle via pre-swizzled source
template <int NROWS>
__device__ __forceinline__ void stage_sw(const ushort* __restrict__ G, size_t ldg,
                                         int row0, int k0, char* lds, int w, int l) {
  constexpr int RPW = NROWS / 4;
  constexpr int ISSUES = RPW / 8;
#pragma unroll
  for (int p = 0; p < ISSUES; ++p) {
    int slot = p * 64 + l;
    int row = w * RPW + (slot >> 3);
    int blk = slot & 7;
    int cb = blk ^ (row & 7);
    const ushort* src = G + (size_t)(row0 + row) * ldg + (size_t)k0 + cb * 8;
    char* db = lds + (w * RPW + p * 8) * 128;
    gload16(src, db);
  }
}

// ---- BK=128 stage: NROWS x 256B rows; swizzle within each 128B half
template <int NROWS>
__device__ __forceinline__ void stage2(const ushort* __restrict__ G, size_t ldg,
                                       int row0, int k0, char* lds, int w, int l) {
  constexpr int RPW = NROWS / 4;
  constexpr int ISSUES = RPW / 4;
#pragma unroll
  for (int p = 0; p < ISSUES; ++p) {
    int row = w * RPW + p * 4 + (l >> 4);
    int blk = l & 15;
    int cb = (blk & 8) | ((blk & 7) ^ (row & 7));
    const ushort* src = G + (size_t)(row0 + row) * ldg + (size_t)k0 + cb * 8;
    char* db = lds + (w * RPW + p * 4) * 256;
    gload16(src, db);
  }
}

// ---------------- BK=64 MFMA core (k_gemm_mem, K=64) ----------------
__device__ __forceinline__ void gemm_core(const ushort* __restrict__ A, size_t lda,
                                          const ushort* __restrict__ Bt, size_t ldb,
                                          int m0, int n0, int kBeg, int kEnd,
                                          char* AsB, char* BsB, int t,
                                          f32x4v acc[2][4]) {
  int w = t >> 6, l = t & 63, lq = l & 15, lg = l >> 4;
  for (int k0 = kBeg; k0 < kEnd; k0 += 64) {
    __syncthreads();
    stage_sw<128>(A, lda, m0, k0, AsB, w, l);
    stage_sw<64>(Bt, ldb, n0, k0, BsB, w, l);
    __syncthreads();
#pragma unroll
    for (int ks = 0; ks < 2; ++ks) {
      bf16x8 af[2], bfr[4];
#pragma unroll
      for (int mt = 0; mt < 2; ++mt) {
        int row = w * 32 + mt * 16 + lq;
        int kb = ks * 64 + lg * 16;
        af[mt] = __builtin_bit_cast(
            bf16x8, *(const u32x4*)(AsB + row * 128 + (kb ^ ((row & 7) << 4))));
      }
#pragma unroll
      for (int nt = 0; nt < 4; ++nt) {
        int row = nt * 16 + lq;
        int kb = ks * 64 + lg * 16;
        bfr[nt] = __builtin_bit_cast(
            bf16x8, *(const u32x4*)(BsB + row * 128 + (kb ^ ((row & 7) << 4))));
      }
#pragma unroll
      for (int mt = 0; mt < 2; ++mt)
#pragma unroll
        for (int nt = 0; nt < 4; ++nt) acc[mt][nt] = mfma16(af[mt], bfr[nt], acc[mt][nt]);
    }
  }
}

// ---------------- BK=128 MFMA core: 128x64 tile, 256B LDS rows ----------------
__device__ __forceinline__ void gemm_core128(const ushort* __restrict__ A, size_t lda,
                                             const ushort* __restrict__ Bt, size_t ldb,
                                             int m0, int n0, int kBeg, int kEnd,
                                             char* AsB, char* BsB, int t,
                                             f32x4v acc[2][4]) {
  int w = t >> 6, l = t & 63, lq = l & 15, lg = l >> 4;
  for (int k0 = kBeg; k0 < kEnd; k0 += 128) {
    __syncthreads();
    stage2<128>(A, lda, m0, k0, AsB, w, l);
    stage2<64>(Bt, ldb, n0, k0, BsB, w, l);
    __syncthreads();
#pragma unroll
    for (int ks = 0; ks < 4; ++ks) {
      int kb = ks * 64 + lg * 16;
      bf16x8 af[2], bfr[4];
#pragma unroll
      for (int mt = 0; mt < 2; ++mt) {
        int row = w * 32 + mt * 16 + lq;
        af[mt] = __builtin_bit_cast(
            bf16x8, *(const u32x4*)(AsB + row * 256 + (kb ^ ((row & 7) << 4))));
      }
#pragma unroll
      for (int nt = 0; nt < 4; ++nt) {
        int row = nt * 16 + lq;
        bfr[nt] = __builtin_bit_cast(
            bf16x8, *(const u32x4*)(BsB + row * 256 + (kb ^ ((row & 7) << 4))));
      }
#pragma unroll
      for (int mt = 0; mt < 2; ++mt)
#pragma unroll
        for (int nt = 0; nt < 4; ++nt) acc[mt][nt] = mfma16(af[mt], bfr[nt], acc[mt][nt]);
    }
  }
}

// ------------- fused prologue prep: enc (1024 blks) + wpeT (16) + pm4 (128)
__global__ __launch_bounds__(256) void k_prep(const float* __restrict__ pm,
                                              const float* __restrict__ wpeW,
                                              ushort* __restrict__ encb,
                                              ushort* __restrict__ wpeT,
                                              float4* __restrict__ pm4) {
  int id = blockIdx.x;
  int t = threadIdx.x;
  if (id < 1024) {
    int row = id * 32 + (t >> 3);
    int kb = (t & 7) * 8;
    ushort o[8];
#pragma unroll
    for (int u = 0; u < 8; ++u) {
      int k = kb + u;
      float val = 0.f;
      if (k < 60) {
        int c = k / 20, jj = k % 20;
        float f = (float)(1 << (jj % 10));
        float a = pm[(size_t)row * 3 + c] * f;
        val = (jj < 10) ? sinf(a) : cosf(a);
      }
      o[u] = f2b(val);
    }
    *(u32x4*)(encb + (size_t)row * 64 + kb) = *(const u32x4*)o;
  } else if (id < 1040) {
    int n = (id - 1024) * 16 + (t >> 4);
    int k = (t & 15) * 4;
    ushort o[4];
#pragma unroll
    for (int u = 0; u < 4; ++u) {
      int kk = k + u;
      o[u] = (kk < 60) ? f2b(wpeW[(size_t)kk * DD + n]) : (ushort)0;
    }
    *(u32x2*)(wpeT + (size_t)n * 64 + k) = *(const u32x2*)o;
  } else {
    int i = (id - 1040) * 256 + t;
    float x = pm[(size_t)i * 3 + 0];
    float y = pm[(size_t)i * 3 + 1];
    float z = pm[(size_t)i * 3 + 2];
    float4 v;
    v.x = x; v.y = y; v.z = z; v.w = x * x + y * y + z * z;
    pm4[i] = v;
  }
}

// -------------------------- memb = bf16(enc@wpeW + wpeb + img) via MFMA, grid (256,4)
__global__ __launch_bounds__(256) void k_gemm_mem(const ushort* __restrict__ encb,
                                                  const ushort* __restrict__ wpeT,
                                                  const float* __restrict__ wpeb,
                                                  const float* __restrict__ img,
                                                  ushort* __restrict__ memb) {
  __shared__ __align__(16) char AsB[16384];
  __shared__ __align__(16) char BsB[8192];
  int m0 = blockIdx.x * 128, n0 = blockIdx.y * 64;
  f32x4v acc[2][4] = {};
  gemm_core(encb, 64, wpeT, 64, m0, n0, 0, 64, AsB, BsB, threadIdx.x, acc);
  int t = threadIdx.x, w = t >> 6, l = t & 63, lq = l & 15, lg = l >> 4;
#pragma unroll
  for (int nt = 0; nt < 4; ++nt) {
    int n = n0 + nt * 16 + lq;
    float bv = wpeb[n];
#pragma unroll
    for (int mt = 0; mt < 2; ++mt) {
      int rowg = m0 + w * 32 + mt * 16 + lg * 4;
      f32x4v a = acc[mt][nt];
#pragma unroll
      for (int r = 0; r < 4; ++r)
        memb[(size_t)(rowg + r) * DD + n] = f2b(a[r] + bv + img[(size_t)(rowg + r) * DD + n]);
    }
  }
}

// ------------------------------- ALL weight transposes f32->bf16^T in ONE dispatch
struct T2BArgs {
  const float* fam[8];
  const float* single[5];  // tpW,tWq,tWk,tWv,tWo
  const float* fW1; const float* fW2;
  ushort* wT; ushort* w1T; ushort* w2T;
};
__global__ __launch_bounds__(256) void k_t2b_all(T2BArgs a) {
  __shared__ ushort T[64][72];
  int id = blockIdx.x;
  const float* src; ushort* dst; int K, N, k0, n0;
  if (id < 768) {
    int fam = id / 96, rem = id % 96, mi = rem >> 4, ti = rem & 15;
    src = a.fam[fam] + (size_t)mi * D2;
    dst = a.wT + (size_t)(fam * 6 + mi) * D2;
    K = DD; N = DD; k0 = (ti >> 2) * 64; n0 = (ti & 3) * 64;
  } else if (id < 848) {
    int j = (id - 768) >> 4, ti = (id - 768) & 15;
    src = a.single[j];
    dst = a.wT + (size_t)(48 + j) * D2;
    K = DD; N = DD; k0 = (ti >> 2) * 64; n0 = (ti & 3) * 64;
  } else if (id < 1616) {
    int t2 = id - 848, mi = t2 >> 7, ti = t2 & 127;
    src = a.fW1 + (size_t)mi * DD * FFD;
    dst = a.w1T + (size_t)mi * DD * FFD;
    K = DD; N = FFD; k0 = (ti >> 5) * 64; n0 = (ti & 31) * 64;
  } else {
    int t2 = id - 1616, mi = t2 >> 7, ti = t2 & 127;
    src = a.fW2 + (size_t)mi * DD * FFD;
    dst = a.w2T + (size_t)mi * DD * FFD;
    K = FFD; N = DD; k0 = (ti >> 2) * 64; n0 = (ti & 3) * 64;
  }
  int t = threadIdx.x;
  int kk = t >> 4, nn4 = (t & 15) * 4;
#pragma unroll
  for (int p = 0; p < 4; ++p) {
    int krow = kk + p * 16;
    float4 v = *(const float4*)(src + (size_t)(k0 + krow) * N + n0 + nn4);
    T[nn4 + 0][krow] = f2b(v.x);
    T[nn4 + 1][krow] = f2b(v.y);
    T[nn4 + 2][krow] = f2b(v.z);
    T[nn4 + 3][krow] = f2b(v.w);
  }
  __syncthreads();
  int nn = t >> 3, kk8 = (t & 7) * 8;
#pragma unroll
  for (int p = 0; p < 2; ++p) {
    int nrow = nn + p * 32;
    u32x4 v = *(const u32x4*)(&T[nrow][kk8]);
    *(u32x4*)(dst + (size_t)(n0 + nrow) * K + k0 + kk8) = v;
  }
}

// ------------------------------------------------------------ flat f32 -> bf16
__global__ __launch_bounds__(256) void k_f2b(const float* __restrict__ in,
                                             ushort* __restrict__ out, int n) {
  int i = (blockIdx.x * 256 + threadIdx.x) * 4;
  if (i + 3 < n) {
    float4 v = *(const float4*)(in + i);
    out[i + 0] = f2b(v.x);
    out[i + 1] = f2b(v.y);
    out[i + 2] = f2b(v.z);
    out[i + 3] = f2b(v.w);
  }
}

// ------ generic MFMA GEMM (K=256, BK=128): OM 0=f32, 1=bf16, 2=bf16+relu, 3=bf16*C1S
template <int OM>
__global__ __launch_bounds__(256) void k_gemm_gen(const ushort* __restrict__ A,
                                                  const ushort* __restrict__ Bt,
                                                  const float* __restrict__ bias,
                                                  void* __restrict__ C, int Nc) {
  __shared__ __align__(16) char AsB[32768];
  __shared__ __align__(16) char BsB[16384];
  int m0 = blockIdx.x * 128, n0 = blockIdx.y * 64;
  f32x4v acc[2][4] = {};
  gemm_core128(A, 256, Bt, 256, m0, n0, 0, 256, AsB, BsB, threadIdx.x, acc);
  int t = threadIdx.x, w = t >> 6, l = t & 63, lq = l & 15, lg = l >> 4;
#pragma unroll
  for (int nt = 0; nt < 4; ++nt) {
    int n = n0 + nt * 16 + lq;
    float bv = bias[n];
#pragma unroll
    for (int mt = 0; mt < 2; ++mt) {
      int rowg = m0 + w * 32 + mt * 16 + lg * 4;
      f32x4v a = acc[mt][nt];
      a[0] += bv; a[1] += bv; a[2] += bv; a[3] += bv;
      if (OM == 2) {
        a[0] = fmaxf(a[0], 0.f); a[1] = fmaxf(a[1], 0.f);
        a[2] = fmaxf(a[2], 0.f); a[3] = fmaxf(a[3], 0.f);
      }
      if (OM == 3) { a[0] *= C1S; a[1] *= C1S; a[2] *= C1S; a[3] *= C1S; }
      if (OM == 0) {
        float* Cf = (float*)C;
#pragma unroll
        for (int r = 0; r < 4; ++r) Cf[(size_t)(rowg + r) * Nc + n] = a[r];
      } else {
        ushort* Cb = (ushort*)C;
#pragma unroll
        for (int r = 0; r < 4; ++r) Cb[(size_t)(rowg + r) * Nc + n] = f2b(a[r]);
      }
    }
  }
}

// ------ dual-output GEMM: text K and V projections in one dispatch, grid (2, 8)
__global__ __launch_bounds__(256) void k_gemm_dual(const ushort* __restrict__ A,
                                                   const ushort* __restrict__ Bt0,
                                                   const ushort* __restrict__ Bt1,
                                                   const float* __restrict__ b0,
                                                   const float* __restrict__ b1,
                                                   float* __restrict__ C0,
                                                   float* __restrict__ C1) {
  __shared__ __align__(16) char AsB[32768];
  __shared__ __align__(16) char BsB[16384];
  int sel = blockIdx.y >> 2;
  int n0 = (blockIdx.y & 3) * 64;
  int m0 = blockIdx.x * 128;
  const ushort* Bt = sel ? Bt1 : Bt0;
  const float* bias = sel ? b1 : b0;
  float* C = sel ? C1 : C0;
  f32x4v acc[2][4] = {};
  gemm_core128(A, 256, Bt, 256, m0, n0, 0, 256, AsB, BsB, threadIdx.x, acc);
  int t = threadIdx.x, w = t >> 6, l = t & 63, lq = l & 15, lg = l >> 4;
#pragma unroll
  for (int nt = 0; nt < 4; ++nt) {
    int n = n0 + nt * 16 + lq;
    float bv = bias[n];
#pragma unroll
    for (int mt = 0; mt < 2; ++mt) {
      int rowg = m0 + w * 32 + mt * 16 + lg * 4;
      f32x4v a = acc[mt][nt];
#pragma unroll
      for (int r = 0; r < 4; ++r) C[(size_t)(rowg + r) * DD + n] = a[r] + bv;
    }
  }
}

// ===== merged self-QKV projection + cross K/V projection, one dispatch, grid 1108 =====
__global__ __launch_bounds__(256) void k_qkv_kv(
    const ushort* __restrict__ xbA, const ushort* __restrict__ Bq,
    const ushort* __restrict__ Bk, const ushort* __restrict__ Bv,
    const float* __restrict__ bq, const float* __restrict__ bk,
    const float* __restrict__ bv, ushort* __restrict__ Qb,
    ushort* __restrict__ Kbs, ushort* __restrict__ Vst,
    const ushort* __restrict__ memb, const ushort* __restrict__ Btk,
    const ushort* __restrict__ Btv, const float* __restrict__ cbk,
    const float* __restrict__ cbv, ushort* __restrict__ Kb,
    ushort* __restrict__ Vt) {
  __shared__ __align__(16) char LB[65536];
  int bid = blockIdx.x;
  int t = threadIdx.x, w = t >> 6, l = t & 63, lq = l & 15, lg = l >> 4;
  if (bid < 84) {
    char* AsB = LB;
    char* BsB = LB + 32768;
    int m0 = (bid % 7) * 128;
    int yy = bid / 7;
    int sel = yy >> 2;
    int n0 = (yy & 3) * 64;
    const ushort* Bt = sel == 0 ? Bq : (sel == 1 ? Bk : Bv);
    const float* bias = sel == 0 ? bq : (sel == 1 ? bk : bv);
    f32x4v acc[2][4] = {};
    gemm_core128(xbA, 256, Bt, 256, m0, n0, 0, 256, AsB, BsB, t, acc);
#pragma unroll
    for (int nt = 0; nt < 4; ++nt) {
      int n = n0 + nt * 16 + lq;
      float bvv = bias[n];
#pragma unroll
      for (int mt = 0; mt < 2; ++mt) {
        int rowg = m0 + w * 32 + mt * 16 + lg * 4;
        f32x4v a = acc[mt][nt];
        a[0] += bvv; a[1] += bvv; a[2] += bvv; a[3] += bvv;
        if (sel == 0) {
#pragma unroll
          for (int r = 0; r < 4; ++r) Qb[(size_t)(rowg + r) * DD + n] = f2b(a[r] * C1S);
        } else if (sel == 1) {
#pragma unroll
          for (int r = 0; r < 4; ++r) Kbs[(size_t)(rowg + r) * DD + n] = f2b(a[r]);
        } else {
          int h = n >> 5, dd = n & 31;
#pragma unroll
          for (int r = 0; r < 4; ++r) {
            int rg = rowg + r;
            if (rg < MM) {
              int b = rg / TT, tq = rg % TT;
              Vst[((size_t)((b * 8 + h) * 32 + dd)) * 128 + tq] = f2b(a[r]);
            }
          }
        }
      }
    }
  } else {
    char* AsB = LB;
    char* BsB = LB + 32768;
    int tile = bid - 84;
    int m0 = (tile & 255) * 128;
    int yy = tile >> 8;
    int isV = yy >= 2;
    int n0 = (yy & 1) * 128;
    const ushort* Bt = isV ? Btv : Btk;
    f32x4v acc[2][8] = {};
    for (int k0 = 0; k0 < 256; k0 += 128) {
      __syncthreads();
      stage2<128>(memb, 256, m0, k0, AsB, w, l);
      stage2<128>(Bt, 256, n0, k0, BsB, w, l);
      __syncthreads();
#pragma unroll
      for (int ks = 0; ks < 4; ++ks) {
        int kb = ks * 64 + lg * 16;
        bf16x8 af[2], bfr[8];
#pragma unroll
        for (int mt = 0; mt < 2; ++mt) {
          int row = w * 32 + mt * 16 + lq;
          af[mt] = __builtin_bit_cast(
              bf16x8, *(const u32x4*)(AsB + row * 256 + (kb ^ ((row & 7) << 4))));
        }
#pragma unroll
        for (int nt = 0; nt < 8; ++nt) {
          int row = nt * 16 + lq;
          bfr[nt] = __builtin_bit_cast(
              bf16x8, *(const u32x4*)(BsB + row * 256 + (kb ^ ((row & 7) << 4))));
        }
#pragma unroll
        for (int mt = 0; mt < 2; ++mt)
#pragma unroll
          for (int nt = 0; nt < 8; ++nt) acc[mt][nt] = mfma16(af[mt], bfr[nt], acc[mt][nt]);
      }
    }
    if (!isV) {
#pragma unroll
      for (int nt = 0; nt < 8; ++nt) {
        int n = n0 + nt * 16 + lq;
        float bvv = cbk[n];
#pragma unroll
        for (int mt = 0; mt < 2; ++mt) {
          int rowg = m0 + w * 32 + mt * 16 + lg * 4;
          f32x4v a = acc[mt][nt];
#pragma unroll
          for (int r = 0; r < 4; ++r) Kb[(size_t)(rowg + r) * DD + n] = f2b(a[r] + bvv);
        }
      }
    } else {
      ushort* T = (ushort*)LB;  // [128][136]
      __syncthreads();
#pragma unroll
      for (int nt = 0; nt < 8; ++nt) {
        int ddl = nt * 16 + lq;
        float bvv = cbv[n0 + ddl];
#pragma unroll
        for (int mt = 0; mt < 2; ++mt) {
          int kl = w * 32 + mt * 16 + lg * 4;
          f32x4v a = acc[mt][nt];
          u32x2 pv;
          pv[0] = pk2(a[0] + bvv, a[1] + bvv);
          pv[1] = pk2(a[2] + bvv, a[3] + bvv);
          *(u32x2*)(T + ddl * 136 + kl) = pv;
        }
      }
      __syncthreads();
      int row = t >> 1, half = t & 1;
      int b = m0 >> 12, key0 = m0 & 4095;
      const ushort* src = T + row * 136 + half * 64;
      ushort* dst = Vt + ((size_t)(b * 256 + n0 + row)) * 4096 + key0 + half * 64;
#pragma unroll
      for (int i = 0; i < 8; ++i)
        *(u32x4*)(dst + i * 8) = *(const u32x4*)(src + i * 8);
    }
  }
}

// ------- o-proj + residual + LN fused: 64x256 tile (full row), BK=128; grid 14; opt. posq
template <int QPROJ>
__global__ __launch_bounds__(256) void k_gemm_o_ln(
    const ushort* __restrict__ A, const ushort* __restrict__ WoT,
    const float* __restrict__ bo, const float* __restrict__ xres,
    const float* __restrict__ g, const float* __restrict__ be,
    float* __restrict__ xout, ushort* __restrict__ xbout,
    const float* __restrict__ Wp, const float* __restrict__ bp,
    float* __restrict__ pqout) {
  __shared__ __align__(16) char LB[81920];  // A 64x256B (16K) + B 256x256B (64K)
  char* AsB = LB;
  char* BsB = LB + 16384;
  int m0 = blockIdx.x * 64;
  int t = threadIdx.x, w = t >> 6, l = t & 63, lq = l & 15, lg = l >> 4;
  f32x4v acc[16] = {};
  for (int k0 = 0; k0 < 256; k0 += 128) {
    __syncthreads();
    stage2<64>(A, 256, m0, k0, AsB, w, l);
    stage2<256>(WoT, 256, 0, k0, BsB, w, l);
    __syncthreads();
#pragma unroll
    for (int ks = 0; ks < 4; ++ks) {
      int kb = ks * 64 + lg * 16;
      int arow = w * 16 + lq;
      bf16x8 af = __builtin_bit_cast(
          bf16x8, *(const u32x4*)(AsB + arow * 256 + (kb ^ ((arow & 7) << 4))));
#pragma unroll
      for (int nt = 0; nt < 16; ++nt) {
        int brow = nt * 16 + lq;
        bf16x8 bf = __builtin_bit_cast(
            bf16x8, *(const u32x4*)(BsB + brow * 256 + (kb ^ ((brow & 7) << 4))));
        acc[nt] = mfma16(af, bf, acc[nt]);
      }
    }
  }
  int rowb = m0 + w * 16 + lg * 4;
  float s[4] = {}, s2[4] = {};
#pragma unroll
  for (int nt = 0; nt < 16; ++nt) {
    int col = nt * 16 + lq;
    float bv = bo[col];
    f32x4v a = acc[nt];
#pragma unroll
    for (int r = 0; r < 4; ++r) {
      a[r] += bv + xres[(size_t)(rowb + r) * DD + col];
      s[r] += a[r];
      s2[r] += a[r] * a[r];
    }
    acc[nt] = a;
  }
#pragma unroll
  for (int r = 0; r < 4; ++r) {
#pragma unroll
    for (int o = 1; o < 16; o <<= 1) {
      s[r] += __shfl_xor(s[r], o, 64);
      s2[r] += __shfl_xor(s2[r], o, 64);
    }
  }
  float mu[4], inv[4];
#pragma unroll
  for (int r = 0; r < 4; ++r) {
    mu[r] = s[r] * (1.f / DD);
    float var = s2[r] * (1.f / DD) - mu[r] * mu[r];
    inv[r] = rsqrtf(var + 1e-5f);
  }
  float pp0[4] = {}, pp1[4] = {}, pp2[4] = {};
#pragma unroll
  for (int nt = 0; nt < 16; ++nt) {
    int col = nt * 16 + lq;
    float gd = g[col], bd = be[col];
    float w0 = 0.f, w1 = 0.f, w2 = 0.f;
    if (QPROJ) { w0 = Wp[col * 3]; w1 = Wp[col * 3 + 1]; w2 = Wp[col * 3 + 2]; }
#pragma unroll
    for (int r = 0; r < 4; ++r) {
      float ln = (acc[nt][r] - mu[r]) * inv[r] * gd + bd;
      xout[(size_t)(rowb + r) * DD + col] = ln;
      xbout[(size_t)(rowb + r) * DD + col] = f2b(ln);
      if (QPROJ) { pp0[r] += ln * w0; pp1[r] += ln * w1; pp2[r] += ln * w2; }
    }
  }
  if (QPROJ) {
#pragma unroll
    for (int r = 0; r < 4; ++r) {
#pragma unroll
      for (int o = 1; o < 16; o <<= 1) {
        pp0[r] += __shfl_xor(pp0[r], o, 64);
        pp1[r] += __shfl_xor(pp1[r], o, 64);
        pp2[r] += __shfl_xor(pp2[r], o, 64);
      }
      if (lq == 0) {
        pqout[(size_t)(rowb + r) * 3 + 0] = pp0[r] + bp[0];
        pqout[(size_t)(rowb + r) * 3 + 1] = pp1[r] + bp[1];
        pqout[(size_t)(rowb + r) * 3 + 2] = pp2[r] + bp[2];
      }
    }
  }
}

// -------------------------------------------- x init (f32 + bf16 mirror)
__global__ __launch_bounds__(256) void k_init_x(const float* __restrict__ qe,
                                                const float* __restrict__ pt,
                                                float* __restrict__ x,
                                                ushort* __restrict__ xb) {
  int r = blockIdx.x, d = threadIdx.x;
  int t = r % TT;
  float v = (t < NQRY) ? qe[t * DD + d] : pt[d];
  x[(size_t)r * DD + d] = v;
  xb[(size_t)r * DD + d] = f2b(v);
}

// ------------------------- text attention (32 keys), f32 in, bf16 out
__global__ __launch_bounds__(128) void k_attn_small(const float* __restrict__ q,
                                                    const float* __restrict__ k,
                                                    const float* __restrict__ v,
                                                    ushort* __restrict__ out,
                                                    int NK) {
  int bh = blockIdx.x;
  int b = bh >> 3, h = bh & 7;
  __shared__ float Ks[TT][HDIM];
  __shared__ float Vs[TT][HDIM];
  for (int i = threadIdx.x; i < NK * HDIM; i += 128) {
    int n = i >> 5, j = i & 31;
    Ks[n][j] = k[(size_t)(b * NK + n) * DD + h * HDIM + j];
    Vs[n][j] = v[(size_t)(b * NK + n) * DD + h * HDIM + j];
  }
  __syncthreads();
  int t = threadIdx.x;
  if (t >= TT) return;
  float qv[HDIM];
  const float* qp = q + (size_t)(b * TT + t) * DD + h * HDIM;
#pragma unroll
  for (int j = 0; j < HDIM; ++j) qv[j] = qp[j];
  const float sc = 0.17677669529663687f * 1.4426950408889634f;
  float l = 0.f, acc[HDIM] = {};
  for (int n = 0; n < NK; ++n) {
    float s = 0.f;
#pragma unroll
    for (int j = 0; j < HDIM; ++j) s += qv[j] * Ks[n][j];
    float p = exp2f(s * sc);
    l += p;
#pragma unroll
    for (int j = 0; j < HDIM; ++j) acc[j] += p * Vs[n][j];
  }
  float inv = 1.f / l;
  ushort* op = out + (size_t)(b * TT + t) * DD + h * HDIM;
#pragma unroll
  for (int j = 0; j < HDIM; ++j) op[j] = f2b(acc[j] * inv);
}

// ---------------- MFMA self-attention (101 keys pad 128, no bias), grid 64
__global__ __launch_bounds__(256) void k_self_mfma(const ushort* __restrict__ Qb,
                                                   const ushort* __restrict__ Kbs,
                                                   const ushort* __restrict__ Vst,
                                                   ushort* __restrict__ out) {
  int bh = blockIdx.x;
  int b = bh >> 3, h = bh & 7;
  int t = threadIdx.x, w = t >> 6, l = t & 63, lq = l & 15, lg = l >> 4;
  __shared__ ushort Plds[4][2][16][40];
  const f32x4v Z = {0.f, 0.f, 0.f, 0.f};
  bf16x8 qfb[2];
  f32x4v oacc[2][2] = {};
  float lsum[2] = {0.f, 0.f};
#pragma unroll
  for (int qi = 0; qi < 2; ++qi) {
    int qidx = (w * 2 + qi) * 16 + lq;
    int qc = qidx < TT ? qidx : TT - 1;
    qfb[qi] = __builtin_bit_cast(
        bf16x8, *(const u32x4*)(Qb + (size_t)(b * TT + qc) * DD + h * HDIM + lg * 8));
  }
  for (int kk = 0; kk < 128; kk += 32) {
    bf16x8 kf[2], vf[2];
#pragma unroll
    for (int t2 = 0; t2 < 2; ++t2) {
      int key = kk + t2 * 16 + lq;
      int kc2 = key < TT ? key : TT - 1;
      kf[t2] = __builtin_bit_cast(
          bf16x8, *(const u32x4*)(Kbs + (size_t)(b * TT + kc2) * DD + h * HDIM + lg * 8));
    }
#pragma unroll
    for (int dt = 0; dt < 2; ++dt)
      vf[dt] = __builtin_bit_cast(
          bf16x8, *(const u32x4*)(Vst + (size_t)(bh * 32 + dt * 16 + lq) * 128 + kk + lg * 8));
#pragma unroll
    for (int qi = 0; qi < 2; ++qi) {
      f32x4v s0 = mfma16(kf[0], qfb[qi], Z);
      f32x4v s1 = mfma16(kf[1], qfb[qi], Z);
      float p[2][4];
#pragma unroll
      for (int t2 = 0; t2 < 2; ++t2) {
#pragma unroll
        for (int r = 0; r < 4; ++r) {
          int kr = kk + t2 * 16 + lg * 4 + r;
          float sv = (t2 == 0) ? s0[r] : s1[r];
          p[t2][r] = (kr < TT) ? exp2f(sv) : 0.f;
        }
        lsum[qi] += (p[t2][0] + p[t2][1]) + (p[t2][2] + p[t2][3]);
      }
      u32x2 w0, w1;
      w0[0] = pk2(p[0][0], p[0][1]);
      w0[1] = pk2(p[0][2], p[0][3]);
      w1[0] = pk2(p[1][0], p[1][1]);
      w1[1] = pk2(p[1][2], p[1][3]);
      *(u32x2*)(&Plds[w][qi][lq][lg * 4]) = w0;
      *(u32x2*)(&Plds[w][qi][lq][16 + lg * 4]) = w1;
      bf16x8 pf = __builtin_bit_cast(bf16x8, *(const u32x4*)(&Plds[w][qi][lq][lg * 8]));
      oacc[qi][0] = mfma16(vf[0], pf, oacc[qi][0]);
      oacc[qi][1] = mfma16(vf[1], pf, oacc[qi][1]);
    }
  }
#pragma unroll
  for (int qi = 0; qi < 2; ++qi) {
    float lv = lsum[qi];
    lv += __shfl_xor(lv, 16, 64);
    lv += __shfl_xor(lv, 32, 64);
    float inv = 1.f / lv;
    int qidx = (w * 2 + qi) * 16 + lq;
    if (qidx < TT) {
      ushort* op = out + (size_t)(b * TT + qidx) * DD + h * HDIM;
#pragma unroll
      for (int dt = 0; dt < 2; ++dt)
#pragma unroll
        for (int r = 0; r < 4; ++r)
          op[dt * 16 + lg * 4 + r] = f2b(oacc[qi][dt][r] * inv);
    }
  }
}

// ----------------------- FFN2 split-K: partials P[z][row][col], grid (7, 4, 8), BK=128
__global__ __launch_bounds__(256) void k_ffn2sk(const ushort* __restrict__ A,
                                                const ushort* __restrict__ Bt,
                                                float* __restrict__ P) {
  __shared__ __align__(16) char AsB[32768];
  __shared__ __align__(16) char BsB[16384];
  int m0 = blockIdx.x * 128, n0 = blockIdx.y * 64, z = blockIdx.z;
  f32x4v acc[2][4] = {};
  gemm_core128(A, FFD, Bt, FFD, m0, n0, z * 256, z * 256 + 256, AsB, BsB, threadIdx.x, acc);
  int t = threadIdx.x, w = t >> 6, l = t & 63, lq = l & 15, lg = l >> 4;
#pragma unroll
  for (int nt = 0; nt < 4; ++nt) {
    int n = n0 + nt * 16 + lq;
#pragma unroll
    for (int mt = 0; mt < 2; ++mt) {
      int rowg = m0 + w * 32 + mt * 16 + lg * 4;
      f32x4v a = acc[mt][nt];
#pragma unroll
      for (int r = 0; r < 4; ++r)
        P[((size_t)z * MMP + rowg + r) * DD + n] = a[r];
    }
  }
}

// -------------------- FFN2 reduce + bias + residual + LN3 -> x, xb
__global__ __launch_bounds__(256) void k_red_ln3(const float* __restrict__ P,
                                                 const float* __restrict__ bias,
                                                 const float* __restrict__ xres,
                                                 const float* __restrict__ g,
                                                 const float* __restrict__ be,
                                                 float* __restrict__ xout,
                                                 ushort* __restrict__ xbout) {
  int row = blockIdx.x, d = threadIdx.x;
  float a = xres[(size_t)row * DD + d] + bias[d];
#pragma unroll
  for (int z = 0; z < 8; ++z) a += P[((size_t)z * MMP + row) * DD + d];
  float s = a, s2 = a * a;
#pragma unroll
  for (int o = 1; o < 64; o <<= 1) {
    s += __shfl_xor(s, o, 64);
    s2 += __shfl_xor(s2, o, 64);
  }
  __shared__ float ws[4], ws2[4];
  int wid = d >> 6;
  if ((d & 63) == 0) { ws[wid] = s; ws2[wid] = s2; }
  __syncthreads();
  s = ws[0] + ws[1] + ws[2] + ws[3];
  s2 = ws2[0] + ws2[1] + ws2[2] + ws2[3];
  float m = s * (1.f / DD);
  float var = s2 * (1.f / DD) - m * m;
  float inv = rsqrtf(var + 1e-5f);
  float r_ = (a - m) * inv * g[d] + be[d];
  xout[(size_t)row * DD + d] = r_;
  xbout[(size_t)row * DD + d] = f2b(r_);
}

// ------------------- MFMA flash cross-attention with distance bias (q pre-scaled bf16)
__global__ __launch_bounds__(256) void k_cross_mfma(
    const ushort* __restrict__ Qb, const ushort* __restrict__ Kb,
    const ushort* __restrict__ Vt, const float* __restrict__ posq,
    const float4* __restrict__ pm4, const float* __restrict__ betaL,
    float* __restrict__ pacc, float* __restrict__ pl) {
  int bh = blockIdx.x, kc = blockIdx.y;
  int b = bh >> 3, h = bh & 7;
  int t = threadIdx.x, w = t >> 6, l = t & 63, lq = l & 15, lg = l >> 4;
  const float L2E = 1.4426950408889634f;
  float spb = log1pf(expf(betaL[h]));
  float cb = spb * L2E;

  __shared__ float4 pm4s[KPC];
  __shared__ ushort Plds[4][2][16][40];

  int kbase = b * NN + kc * KPC;
  for (int i = t; i < KPC; i += 256) pm4s[i] = pm4[kbase + i];
  __syncthreads();

  const f32x4v Z = {0.f, 0.f, 0.f, 0.f};
  bf16x8 qfb[2];
  float a0[2], px[2], py[2], pz[2];
  f32x4v oacc[2][2] = {};
  float lsum[2] = {0.f, 0.f};

#pragma unroll
  for (int qi = 0; qi < 2; ++qi) {
    int qt = w * 2 + qi;
    int qidx = qt * 16 + lq;
    int qc = qidx < TT ? qidx : TT - 1;
    size_t xr = (size_t)(b * TT + qc);
    qfb[qi] = __builtin_bit_cast(
        bf16x8, *(const u32x4*)(Qb + xr * 256 + h * 32 + lg * 8));
    float qx = posq[xr * 3 + 0], qy = posq[xr * 3 + 1], qz = posq[xr * 3 + 2];
    a0[qi] = -cb * (qx * qx + qy * qy + qz * qz);
    px[qi] = 2.f * cb * qx;
    py[qi] = 2.f * cb * qy;
    pz[qi] = 2.f * cb * qz;
  }

  for (int kk = 0; kk < KPC; kk += 32) {
    bf16x8 kf[2], vf[2];
#pragma unroll
    for (int t2 = 0; t2 < 2; ++t2)
      kf[t2] = __builtin_bit_cast(
          bf16x8, *(const u32x4*)(Kb + (size_t)(kbase + kk + t2 * 16 + lq) * 256 +
                                  h * 32 + lg * 8));
#pragma unroll
    for (int dt = 0; dt < 2; ++dt)
      vf[dt] = __builtin_bit_cast(
          bf16x8, *(const u32x4*)(Vt + (size_t)(bh * 32 + dt * 16 + lq) * 4096 +
                                  kc * KPC + kk + lg * 8));
    float bx[2][4], by[2][4], bz[2][4], b0[2][4];
#pragma unroll
    for (int t2 = 0; t2 < 2; ++t2)
#pragma unroll
      for (int r = 0; r < 4; ++r) {
        float4 pv = pm4s[kk + t2 * 16 + lg * 4 + r];
        bx[t2][r] = pv.x; by[t2][r] = pv.y; bz[t2][r] = pv.z;
        b0[t2][r] = cb * pv.w;
      }
#pragma unroll
    for (int qi = 0; qi < 2; ++qi) {
      f32x4v s0 = mfma16(kf[0], qfb[qi], Z);
      f32x4v s1 = mfma16(kf[1], qfb[qi], Z);
      float p[2][4];
#pragma unroll
      for (int t2 = 0; t2 < 2; ++t2) {
#pragma unroll
        for (int r = 0; r < 4; ++r) {
          float sv = (t2 == 0) ? s0[r] : s1[r];
          float bias = fmaf(px[qi], bx[t2][r],
                       fmaf(py[qi], by[t2][r],
                       fmaf(pz[qi], bz[t2][r], a0[qi] - b0[t2][r])));
          p[t2][r] = exp2f(sv + bias);
        }
        lsum[qi] += (p[t2][0] + p[t2][1]) + (p[t2][2] + p[t2][3]);
      }
      u32x2 w0, w1;
      w0[0] = pk2(p[0][0], p[0][1]);
      w0[1] = pk2(p[0][2], p[0][3]);
      w1[0] = pk2(p[1][0], p[1][1]);
      w1[1] = pk2(p[1][2], p[1][3]);
      *(u32x2*)(&Plds[w][qi][lq][lg * 4]) = w0;
      *(u32x2*)(&Plds[w][qi][lq][16 + lg * 4]) = w1;
      bf16x8 pf = __builtin_bit_cast(bf16x8, *(const u32x4*)(&Plds[w][qi][lq][lg * 8]));
      oacc[qi][0] = mfma16(vf[0], pf, oacc[qi][0]);
      oacc[qi][1] = mfma16(vf[1], pf, oacc[qi][1]);
    }
  }

#pragma unroll
  for (int qi = 0; qi < 2; ++qi) {
    float lv = lsum[qi];
    lv += __shfl_xor(lv, 16, 64);
    lv += __shfl_xor(lv, 32, 64);
    int qt = w * 2 + qi;
    int qidx = qt * 16 + lq;
    if (qidx < TT) {
      size_t o = ((size_t)(kc * 64 + bh) * TT + qidx) * 32;
#pragma unroll
      for (int dt = 0; dt < 2; ++dt) {
        f32x4v a = oacc[qi][dt];
        float4 st;
        st.x = a[0]; st.y = a[1]; st.z = a[2]; st.w = a[3];
        *(float4*)(pacc + o + dt * 16 + lg * 4) = st;
      }
      if (lg == 0) pl[(size_t)(kc * 64 + bh) * TT + qidx] = lv;
    }
  }
}

// -------------------------- merge key-chunk partials -> bf16 attn out
__global__ __launch_bounds__(256) void k_cross_merge(const float* __restrict__ pacc,
                                                     const float* __restrict__ pl,
                                                     ushort* __restrict__ out) {
  int bh = blockIdx.x;
  int b = bh >> 3, h = bh & 7;
  int q8 = blockIdx.y * 8 + (threadIdx.x >> 5);
  int j = threadIdx.x & 31;
  if (q8 >= TT) return;
  float sa = 0.f, sl = 0.f;
  for (int kc = 0; kc < KC; ++kc) {
    sa += pacc[(((size_t)kc * 64 + bh) * TT + q8) * HDIM + j];
    sl += pl[((size_t)kc * 64 + bh) * TT + q8];
  }
  out[((size_t)(b * TT + q8)) * DD + h * HDIM + j] = f2b(sa / sl);
}

// ------------------------ final LN + scatter to hs / pres
__global__ __launch_bounds__(256) void k_fin(const float* __restrict__ x,
                                             const float* __restrict__ g,
                                             const float* __restrict__ be,
                                             float* __restrict__ hs,
                                             float* __restrict__ pres) {
  int row = blockIdx.x, d = threadIdx.x;
  int b = row / TT, tq = row % TT;
  float v = x[(size_t)row * DD + d];
  float s = v, s2 = v * v;
#pragma unroll
  for (int o = 1; o < 64; o <<= 1) {
    s += __shfl_xor(s, o, 64);
    s2 += __shfl_xor(s2, o, 64);
  }
  __shared__ float ws[4], ws2[4];
  int wid = d >> 6;
  if ((d & 63) == 0) { ws[wid] = s; ws2[wid] = s2; }
  __syncthreads();
  s = ws[0] + ws[1] + ws[2] + ws[3];
  s2 = ws2[0] + ws2[1] + ws2[2] + ws2[3];
  float m = s * (1.f / DD);
  float var = s2 * (1.f / DD) - m * m;
  float inv = rsqrtf(var + 1e-5f);
  float r = (v - m) * inv * g[d] + be[d];
  if (tq < NQRY) hs[((size_t)(b * NQRY + tq)) * DD + d] = r;
  else pres[(size_t)b * DD + d] = r;
}

// ----------------------- parallel presence-MLP stage: out[8][256] = relu(in@W + b)
__global__ __launch_bounds__(256) void k_mlp8(const float* __restrict__ in,
                                              const float* __restrict__ W,
                                              const float* __restrict__ b,
                                              float* __restrict__ out) {
  __shared__ float ins[8][DD];
  __shared__ float red[8][32][8];  // [ks][c][r]
  int t = threadIdx.x;
  for (int i = t; i < 8 * DD; i += 256) ins[i >> 8][i & 255] = in[i];
  __syncthreads();
  int c = t & 31, ks = t >> 5;
  int cg = blockIdx.x * 32 + c;
  float acc[8] = {};
  for (int k = ks * 32; k < ks * 32 + 32; ++k) {
    float w = W[(size_t)k * DD + cg];
#pragma unroll
    for (int r = 0; r < 8; ++r) acc[r] += ins[r][k] * w;
  }
#pragma unroll
  for (int r = 0; r < 8; ++r) red[ks][c][r] = acc[r];
  __syncthreads();
  int c2 = t & 31, r2 = t >> 5;
  float s = 0.f;
#pragma unroll
  for (int k2 = 0; k2 < 8; ++k2) s += red[k2][c2][r2];
  s = fmaxf(s + b[blockIdx.x * 32 + c2], 0.f);
  out[(size_t)r2 * DD + blockIdx.x * 32 + c2] = s;
}

__global__ __launch_bounds__(256) void k_logit(const float* __restrict__ h2,
                                               const float* __restrict__ W3,
                                               const float* __restrict__ b3,
                                               float* __restrict__ out) {
  int r = threadIdx.x >> 5, lane = threadIdx.x & 31;
  float s = 0.f;
  for (int k = lane; k < DD; k += 32) s += h2[r * DD + k] * W3[k];
#pragma unroll
  for (int o = 16; o; o >>= 1) s += __shfl_xor(s, o, 32);
  if (lane == 0) out[r] = s + b3[0];
}

// =======================================================================================
extern "C" void kernel_launch(void* const* d_in, const int* in_sizes, int n_in,
                              void* d_out, int out_size, void* d_ws, size_t ws_size,
                              hipStream_t stream) {
  (void)in_sizes; (void)n_in; (void)out_size; (void)ws_size;
  auto F = [&](int i) { return (const float*)d_in[i]; };
  const float* img   = F(0);
  const float* txtf  = F(1);
  const float* pm    = F(2);
  const float* qe    = F(3);
  const float* ptok  = F(4);
  const float* tpW   = F(5);
  const float* tpb   = F(6);
  const float* tWq   = F(7);  const float* tbq = F(8);
  const float* tWk   = F(9);  const float* tbk = F(10);
  const float* tWv   = F(11); const float* tbv = F(12);
  const float* tWo   = F(13); const float* tbo = F(14);
  const float* tlng  = F(15); const float* tlnb = F(16);
  const float* wpeW  = F(17); const float* wpeb = F(18);
  const float* saWq  = F(19); const float* sabq = F(20);
  const float* saWk  = F(21); const float* sabk = F(22);
  const float* saWv  = F(23); const float* sabv = F(24);
  const float* saWo  = F(25); const float* sabo = F(26);
  const float* caWq  = F(27); const float* cabq = F(28);
  const float* caWk  = F(29); const float* cabk = F(30);
  const float* caWv  = F(31); const float* cabv = F(32);
  const float* caWo  = F(33); const float* cabo = F(34);
  const float* fW1   = F(35); const float* fb1 = F(36);
  const float* fW2   = F(37); const float* fb2 = F(38);
  const float* ln1g  = F(39); const float* ln1b = F(40);
  const float* ln2g  = F(41); const float* ln2b = F(42);
  const float* ln3g  = F(43); const float* ln3b = F(44);
  const float* posW  = F(45); const float* posb = F(46);
  const float* beta  = F(47);
  const float* fing  = F(48); const float* finb = F(49);
  const float* pW1   = F(50); const float* pb1 = F(51);
  const float* pW2   = F(52); const float* pb2 = F(53);
  const float* pW3   = F(54); const float* pb3 = F(55);

  char* wp = (char*)d_ws;
  auto alloc = [&](size_t bytes) {
    char* p = wp;
    wp += (bytes + 255) & ~(size_t)255;
    return (void*)p;
  };
  ushort* memb = (ushort*)alloc((size_t)BNN * DD * 2);
  ushort* Kb   = (ushort*)alloc((size_t)BNN * DD * 2);
  ushort* Vt   = (ushort*)alloc((size_t)64 * 32 * 4096 * 2);
  ushort* encb = (ushort*)alloc((size_t)BNN * 64 * 2);
  ushort* wT   = (ushort*)alloc((size_t)53 * D2 * 2);
  ushort* w1T  = (ushort*)alloc((size_t)6 * FFD * DD * 2);
  ushort* w2T  = (ushort*)alloc((size_t)6 * DD * FFD * 2);
  ushort* xb   = (ushort*)alloc((size_t)MMP * DD * 2);
  ushort* hb   = (ushort*)alloc((size_t)MMP * FFD * 2);
  ushort* tDb  = (ushort*)alloc((size_t)MMP * DD * 2);
  ushort* tQb  = (ushort*)alloc((size_t)MMP * DD * 2);
  ushort* tKb  = (ushort*)alloc((size_t)MMP * DD * 2);
  ushort* tQb2 = (ushort*)alloc((size_t)MMP * DD * 2);
  ushort* Vst  = (ushort*)alloc((size_t)64 * 32 * 128 * 2);
  ushort* txtb = (ushort*)alloc((size_t)BB * NTXT * DD * 2);
  ushort* txtb2= (ushort*)alloc((size_t)BB * NTXT * DD * 2);
  float* fp2  = (float*)alloc((size_t)8 * MMP * DD * 4);
  float* x    = (float*)alloc((size_t)MMP * DD * 4);
  float* tA   = (float*)alloc((size_t)MMP * DD * 4);
  float* tK   = (float*)alloc((size_t)BB * NTXT * DD * 4);
  float* tV   = (float*)alloc((size_t)BB * NTXT * DD * 4);
  float* pacc = (float*)alloc((size_t)(KC * 64 + 8) * TT * HDIM * 4);
  float* pl   = (float*)alloc((size_t)(KC * 64 + 8) * TT * 4);
  float* posq = (float*)alloc((size_t)4096 * 4);
  float4* pm4 = (float4*)alloc((size_t)BNN * 16);
  float* pres = (float*)alloc((size_t)BB * DD * 4);
  float* ph1  = (float*)alloc((size_t)BB * DD * 4);
  float* ph2  = (float*)alloc((size_t)BB * DD * 4);
  ushort* wpeT = (ushort*)alloc((size_t)DD * 64 * 2);

  // ---- prologue
  k_prep<<<1168, 256, 0, stream>>>(pm, wpeW, encb, wpeT, pm4);
  T2BArgs ta;
  ta.fam[0] = saWq; ta.fam[1] = saWk; ta.fam[2] = saWv; ta.fam[3] = saWo;
  ta.fam[4] = caWq; ta.fam[5] = caWk; ta.fam[6] = caWv; ta.fam[7] = caWo;
  ta.single[0] = tpW; ta.single[1] = tWq; ta.single[2] = tWk;
  ta.single[3] = tWv; ta.single[4] = tWo;
  ta.fW1 = fW1; ta.fW2 = fW2; ta.wT = wT; ta.w1T = w1T; ta.w2T = w2T;
  k_t2b_all<<<2384, 256, 0, stream>>>(ta);
  k_gemm_mem<<<dim3(256, 4), 256, 0, stream>>>(encb, wpeT, wpeb, img, memb);

  // ---- phase 0: text block
  k_f2b<<<(BB * NTXT * DD) / 1024, 256, 0, stream>>>(txtf, txtb, BB * NTXT * DD);
  k_gemm_gen<1><<<dim3(2, 4), 256, 0, stream>>>(txtb, wT + (size_t)48 * D2, tpb, txtb2, DD);
  k_gemm_dual<<<dim3(2, 8), 256, 0, stream>>>(txtb2, wT + (size_t)50 * D2,
                                              wT + (size_t)51 * D2, tbk, tbv, tK, tV);
  k_init_x<<<MM, 256, 0, stream>>>(qe, ptok, x, xb);
  k_gemm_gen<0><<<dim3(7, 4), 256, 0, stream>>>(xb, wT + (size_t)49 * D2, tbq, tA, DD);
  k_attn_small<<<64, 128, 0, stream>>>(tA, tK, tV, tDb, NTXT);
  k_gemm_o_ln<0><<<14, 256, 0, stream>>>(tDb, wT + (size_t)52 * D2, tbo, x, tlng, tlnb,
                                         x, xb, nullptr, nullptr, nullptr);

  for (int i = 0; i < NLAY; ++i) {
    int iD = i * DD;
    // self-QKV (84 blocks) + cross-K/V of memb (1024 blocks) co-dispatched
    k_qkv_kv<<<1108, 256, 0, stream>>>(
        xb, wT + (size_t)(0 + i) * D2, wT + (size_t)(6 + i) * D2, wT + (size_t)(12 + i) * D2,
        sabq + iD, sabk + iD, sabv + iD, tQb, tKb, Vst,
        memb, wT + (size_t)(30 + i) * D2, wT + (size_t)(36 + i) * D2,
        cabk + iD, cabv + iD, Kb, Vt);
    k_self_mfma<<<64, 256, 0, stream>>>(tQb, tKb, Vst, tDb);
    // o-proj + LN1 + posq
    k_gemm_o_ln<1><<<14, 256, 0, stream>>>(tDb, wT + (size_t)(18 + i) * D2, sabo + iD,
                                           x, ln1g + iD, ln1b + iD, x, xb,
                                           posW + (size_t)i * DD * 3, posb + i * 3, posq);
    // cross-q projection (scaled bf16)
    k_gemm_gen<3><<<dim3(7, 4), 256, 0, stream>>>(xb, wT + (size_t)(24 + i) * D2,
                                                  cabq + iD, tQb2, DD);
    k_cross_mfma<<<dim3(64, KC), 256, 0, stream>>>(tQb2, Kb, Vt, posq, pm4,
                                                   beta + i * NH, pacc, pl);
    k_cross_merge<<<dim3(64, 13), 256, 0, stream>>>(pacc, pl, tDb);
    k_gemm_o_ln<0><<<14, 256, 0, stream>>>(tDb, wT + (size_t)(42 + i) * D2, cabo + iD,
                                           x, ln2g + iD, ln2b + iD, x, xb,
                                           nullptr, nullptr, nullptr);
    // FFN
    k_gemm_gen<2><<<dim3(7, 32), 256, 0, stream>>>(xb, w1T + (size_t)i * DD * FFD,
                                                   fb1 + i * FFD, hb, FFD);
    k_ffn2sk<<<dim3(7, 4, 8), 256, 0, stream>>>(hb, w2T + (size_t)i * DD * FFD, fp2);
    k_red_ln3<<<MM, 256, 0, stream>>>(fp2, fb2 + iD, x, ln3g + iD, ln3b + iD, x, xb);
  }

  // ---- epilogue
  k_fin<<<MM, 256, 0, stream>>>(x, fing, finb, (float*)d_out, pres);
  k_mlp8<<<8, 256, 0, stream>>>(pres, pW1, pb1, ph1);
  k_mlp8<<<8, 256, 0, stream>>>(ph1, pW2, pb2, ph2);
  k_logit<<<1, 256, 0, stream>>>(ph2, pW3, pb3, (float*)d_out + (size_t)BB * NQRY * DD);
}